// Round 1
// baseline (1792.950 us; speedup 1.0000x reference)
//
#include <hip/hip_runtime.h>
#include <hip/hip_bf16.h>

// NSA forward: B=2, N=1024, D=2048, H=16, HD=128, BS=64, SEL=8, WIN=64
#define HN   16
#define HDIM 128
#define NSEQ 1024
#define NBLK 16
#define BSZ  64
#define DM   2048
#define SCALE 0.08838834764831845f

// ------------------------------------------------------------------
// fp32 GEMM: C[M][N] = A[M][K] @ B[K][N].  64x64 tile, 4x4 microtile.
// ------------------------------------------------------------------
__global__ __launch_bounds__(256) void gemm_f32(const float* __restrict__ A,
                                                const float* __restrict__ B,
                                                float* __restrict__ C,
                                                int M, int N, int K) {
  __shared__ float As[16][68];  // [kk][row], pad 68 -> 2-way max on write
  __shared__ float Bs[16][68];  // [kk][col]
  const int t  = threadIdx.x;
  const int tx = t & 15, ty = t >> 4;
  const int row0 = blockIdx.y * 64;
  const int col0 = blockIdx.x * 64;
  float acc[4][4] = {{0.f, 0.f, 0.f, 0.f}};
  const int kkA = t & 15, rA = t >> 4;  // A staging coords
  const int cB  = t & 63, kB = t >> 6;  // B staging coords
  for (int k0 = 0; k0 < K; k0 += 16) {
#pragma unroll
    for (int j = 0; j < 4; ++j) {
      int rr = rA + 16 * j;
      As[kkA][rr] = A[(size_t)(row0 + rr) * K + (k0 + kkA)];
    }
#pragma unroll
    for (int j = 0; j < 4; ++j) {
      int kk2 = kB + 4 * j;
      int gc  = col0 + cB;
      Bs[kk2][cB] = (gc < N) ? B[(size_t)(k0 + kk2) * N + gc] : 0.f;
    }
    __syncthreads();
#pragma unroll
    for (int kq = 0; kq < 16; ++kq) {
      const float4 av = *(const float4*)&As[kq][ty * 4];
      const float4 bv = *(const float4*)&Bs[kq][tx * 4];
      const float a[4] = {av.x, av.y, av.z, av.w};
      const float b[4] = {bv.x, bv.y, bv.z, bv.w};
#pragma unroll
      for (int i = 0; i < 4; ++i)
#pragma unroll
        for (int jj = 0; jj < 4; ++jj) acc[i][jj] += a[i] * b[jj];
    }
    __syncthreads();
  }
#pragma unroll
  for (int i = 0; i < 4; ++i) {
    const int row = row0 + ty * 4 + i;
#pragma unroll
    for (int jj = 0; jj < 4; ++jj) {
      const int col = col0 + tx * 4 + jj;
      if (col < N) C[(size_t)row * N + col] = acc[i][jj];
    }
  }
}

// ------------------------------------------------------------------
__global__ __launch_bounds__(256) void sigmoid_k(float* __restrict__ p, int n) {
  int i = blockIdx.x * 256 + threadIdx.x;
  if (i < n) p[i] = 1.0f / (1.0f + __expf(-p[i]));
}

// ------------------------------------------------------------------
// RoPE in place on [B][N][H][HD]; one thread per (b,n,h,d<64) pair.
// ------------------------------------------------------------------
__global__ __launch_bounds__(256) void rope_inplace(float* __restrict__ p) {
  int i = blockIdx.x * 256 + threadIdx.x;  // B*N*H*64 = 2097152
  int d = i & 63;
  int h = (i >> 6) & 15;
  int n = (i >> 10) & 1023;
  int b = i >> 20;
  float* base = p + ((size_t)((b * NSEQ + n) * HN + h) << 7) + d;
  // inv = 10000^(-d/64) = exp(-d * ln(10000)/64)
  float inv = expf(-(float)d * (9.210340371976184f / 64.0f));
  float th = (float)n * inv;
  float sn, cs;
  sincosf(th, &sn, &cs);
  float t1 = base[0], t2 = base[64];
  base[0]  = t1 * cs - t2 * sn;
  base[64] = t1 * sn + t2 * cs;
}

// ------------------------------------------------------------------
// Block mean: dst[b][m][h][d] = mean_j src[b][m*64+j][h][d]
// ------------------------------------------------------------------
__global__ __launch_bounds__(256) void block_mean(const float* __restrict__ src,
                                                  float* __restrict__ dst) {
  int i = blockIdx.x * 256 + threadIdx.x;  // B*NBLK*H*HD = 65536
  int d = i & 127;
  int h = (i >> 7) & 15;
  int m = (i >> 11) & 15;
  int b = i >> 15;
  const float* p = src + ((size_t)((b * NSEQ + m * BSZ) * HN + h) << 7) + d;
  float acc = 0.f;
#pragma unroll 8
  for (int j = 0; j < 64; ++j) acc += p[(size_t)j * (HN * HDIM)];
  dst[i] = acc * (1.0f / 64.0f);
}

// ------------------------------------------------------------------
// Compressed attention probs + top-8 block selection.
// One thread per (b,h,n). pc layout [b][h][n][16]; sel bitmask per row.
// ------------------------------------------------------------------
__global__ __launch_bounds__(256) void cmp_sel(const float* __restrict__ q,
                                               const float* __restrict__ kc,
                                               float* __restrict__ pc,
                                               int* __restrict__ sel) {
  int i = blockIdx.x * 256 + threadIdx.x;  // B*H*N = 32768
  int n = i & 1023;
  int h = (i >> 10) & 15;
  int b = i >> 14;
  const float* qp = q + ((size_t)((b * NSEQ + n) * HN + h) << 7);
  const int nv = (n + 1) >> 6;  // # fully-past (valid) blocks
  float s[NBLK];
  float mx = -1e30f;
  for (int m = 0; m < nv; ++m) {
    const float* kp = kc + ((size_t)((b * NBLK + m) * HN + h) << 7);
    float dot = 0.f;
    for (int d = 0; d < HDIM; d += 4) {
      const float4 qv = *(const float4*)&qp[d];
      const float4 kv = *(const float4*)&kp[d];
      dot += qv.x * kv.x + qv.y * kv.y + qv.z * kv.z + qv.w * kv.w;
    }
    s[m] = dot * SCALE;
    mx = fmaxf(mx, s[m]);
  }
  float den = 0.f;
  for (int m = 0; m < nv; ++m) { s[m] = __expf(s[m] - mx); den += s[m]; }
  const float rden = (nv > 0) ? 1.0f / den : 0.f;
  float p[NBLK];
#pragma unroll
  for (int m = 0; m < NBLK; ++m) p[m] = (m < nv) ? s[m] * rden : 0.f;
  float* pout = pc + (size_t)i * NBLK;
#pragma unroll
  for (int m = 0; m < NBLK; ++m) pout[m] = p[m];
  // importance = p + 2 * onehot(current block); top-8, ties -> lowest index
  p[n >> 6] += 2.0f;
  int mask = 0;
#pragma unroll
  for (int ss = 0; ss < 8; ++ss) {
    int best = 0;
    float bv = -1e30f;
#pragma unroll
    for (int m = 0; m < NBLK; ++m)
      if (p[m] > bv) { bv = p[m]; best = m; }
    mask |= 1 << best;
    p[best] = -1e30f;
  }
  sel[i] = mask;
}

// ------------------------------------------------------------------
// Fused slc + swa + cmp-output attention.
// Block = 256 threads = one (b,h,16-row tile). Single-pass softmax
// (scores bounded, no overflow). Skips column tiles with no
// selected-block / window overlap for any row in the tile.
// ------------------------------------------------------------------
__global__ __launch_bounds__(256) void attn_fused(
    const float* __restrict__ q, const float* __restrict__ k,
    const float* __restrict__ v, const float* __restrict__ vc,
    const float* __restrict__ pc, const int* __restrict__ sel,
    const float* __restrict__ g, float* __restrict__ o) {
  const int rt = blockIdx.x, h = blockIdx.y, b = blockIdx.z;
  const int t  = threadIdx.x;
  const int r  = t >> 4;   // row in tile (0..15)
  const int c8 = t & 15;   // dim chunk: dims [c8*8, c8*8+8)
  const int nbase = rt * 16;

  __shared__ float q_s[16][128];
  __shared__ float kv_s[64][132];
  __shared__ float e_s[16][66];
  __shared__ float p_s[16][16];
  __shared__ int   sel_s[16];

#pragma unroll
  for (int it = 0; it < 2; ++it) {
    int idx = t + 256 * it;
    int rr = idx >> 5, d4 = idx & 31;
    *(float4*)&q_s[rr][d4 * 4] =
        *(const float4*)&q[((size_t)((b * NSEQ + nbase + rr) * HN + h) << 7) + d4 * 4];
  }
  p_s[r][c8] = pc[((size_t)((b * HN + h) * NSEQ) + nbase + r) * NBLK + c8];
  if (t < 16) sel_s[t] = sel[(size_t)(b * HN + h) * NSEQ + nbase + t];
  __syncthreads();

  const int n = nbase + r;
  float accs[8] = {0.f, 0.f, 0.f, 0.f, 0.f, 0.f, 0.f, 0.f};
  float accw[8] = {0.f, 0.f, 0.f, 0.f, 0.f, 0.f, 0.f, 0.f};
  float dens = 0.f, denw = 0.f;
  const int ntiles = (nbase + 15) / 64 + 1;

  for (int ct = 0; ct < ntiles; ++ct) {
    const int cbase = ct * 64;
    // block-uniform skip check (all threads compute identical f)
    int f = 0;
#pragma unroll
    for (int rr = 0; rr < 16; ++rr) {
      const int nn = nbase + rr;
      f |= (cbase <= nn) &&
           ((((sel_s[rr] >> ct) & 1) != 0) || (cbase + 63 >= nn - 64));
    }
    if (!f) continue;

    // stage K tile
#pragma unroll
    for (int it = 0; it < 8; ++it) {
      int idx = t + 256 * it;
      int j = idx >> 5, d4 = idx & 31;
      *(float4*)&kv_s[j][d4 * 4] =
          *(const float4*)&k[((size_t)((b * NSEQ + cbase + j) * HN + h) << 7) + d4 * 4];
    }
    __syncthreads();

    // scores: thread (r, c8) covers cols c8 + 16*pp
    float sc[4] = {0.f, 0.f, 0.f, 0.f};
    for (int d0 = 0; d0 < 128; d0 += 4) {
      const float4 qv = *(const float4*)&q_s[r][d0];
#pragma unroll
      for (int pp = 0; pp < 4; ++pp) {
        const float4 kv = *(const float4*)&kv_s[c8 + 16 * pp][d0];
        sc[pp] += qv.x * kv.x + qv.y * kv.y + qv.z * kv.z + qv.w * kv.w;
      }
    }
#pragma unroll
    for (int pp = 0; pp < 4; ++pp)
      e_s[r][c8 + 16 * pp] = __expf(sc[pp] * SCALE);
    __syncthreads();

    // stage V tile (reuse kv_s)
#pragma unroll
    for (int it = 0; it < 8; ++it) {
      int idx = t + 256 * it;
      int j = idx >> 5, d4 = idx & 31;
      *(float4*)&kv_s[j][d4 * 4] =
          *(const float4*)&v[((size_t)((b * NSEQ + cbase + j) * HN + h) << 7) + d4 * 4];
    }
    __syncthreads();

    // accumulate
    const bool slc_on = ((sel_s[r] >> ct) & 1) != 0;
    const int jmax = min(64, n - cbase + 1);  // causal bound
    for (int j = 0; j < jmax; ++j) {
      const float e = e_s[r][j];
      float vv[8];
      *(float4*)&vv[0] = *(const float4*)&kv_s[j][c8 * 8];
      *(float4*)&vv[4] = *(const float4*)&kv_s[j][c8 * 8 + 4];
      if (slc_on) {
        dens += e;
#pragma unroll
        for (int ii = 0; ii < 8; ++ii) accs[ii] += e * vv[ii];
      }
      if (n - (cbase + j) <= 64) {
        denw += e;
#pragma unroll
        for (int ii = 0; ii < 8; ++ii) accw[ii] += e * vv[ii];
      }
    }
    __syncthreads();
  }

  // compressed-branch output: o_cmp = sum_m p_cmp[m] * v_cmp[m]
  float accc[8] = {0.f, 0.f, 0.f, 0.f, 0.f, 0.f, 0.f, 0.f};
#pragma unroll
  for (int m = 0; m < NBLK; ++m) {
    const float pcm = p_s[r][m];
    if (pcm != 0.f) {
      const float* vp = vc + ((size_t)((b * NBLK + m) * HN + h) << 7) + c8 * 8;
      const float4 v0 = *(const float4*)&vp[0];
      const float4 v1 = *(const float4*)&vp[4];
      accc[0] += pcm * v0.x; accc[1] += pcm * v0.y;
      accc[2] += pcm * v0.z; accc[3] += pcm * v0.w;
      accc[4] += pcm * v1.x; accc[5] += pcm * v1.y;
      accc[6] += pcm * v1.z; accc[7] += pcm * v1.w;
    }
  }

  const size_t grow = (size_t)(b * NSEQ + n) * 48;
  const float gc = g[grow + h];
  const float gs = g[grow + 16 + h];
  const float gw = g[grow + 32 + h];
  const float is = 1.0f / dens;  // current block always selected -> dens > 0
  const float iw = 1.0f / denw;  // m = n always in window       -> denw > 0
  float out[8];
#pragma unroll
  for (int ii = 0; ii < 8; ++ii)
    out[ii] = gc * accc[ii] + gs * accs[ii] * is + gw * accw[ii] * iw;
  float* op = o + ((size_t)((b * NSEQ + n) * HN + h) << 7) + c8 * 8;
  *(float4*)&op[0] = make_float4(out[0], out[1], out[2], out[3]);
  *(float4*)&op[4] = make_float4(out[4], out[5], out[6], out[7]);
}

// ------------------------------------------------------------------
extern "C" void kernel_launch(void* const* d_in, const int* in_sizes, int n_in,
                              void* d_out, int out_size, void* d_ws, size_t ws_size,
                              hipStream_t stream) {
  const float* x  = (const float*)d_in[0];
  const float* Wq = (const float*)d_in[1];
  const float* Wk = (const float*)d_in[2];
  const float* Wv = (const float*)d_in[3];
  const float* Wg = (const float*)d_in[4];
  const float* Wo = (const float*)d_in[5];
  float* out = (float*)d_out;

  float* ws = (float*)d_ws;
  float* q  = ws;              // 4194304
  float* k  = q + 4194304;     // 4194304
  float* v  = k + 4194304;     // 4194304
  float* o  = v + 4194304;     // 4194304
  float* g  = o + 4194304;     // 98304
  float* kc = g + 98304;       // 65536
  float* vc = kc + 65536;      // 65536
  float* pc = vc + 65536;      // 524288
  int* sel  = (int*)(pc + 524288);  // 32768 ints
  // total ~70.3 MB of workspace

  const dim3 blk(256);
  gemm_f32<<<dim3(32, 32), blk, 0, stream>>>(x, Wq, q, 2048, 2048, 2048);
  gemm_f32<<<dim3(32, 32), blk, 0, stream>>>(x, Wk, k, 2048, 2048, 2048);
  gemm_f32<<<dim3(32, 32), blk, 0, stream>>>(x, Wv, v, 2048, 2048, 2048);
  gemm_f32<<<dim3(1, 32),  blk, 0, stream>>>(x, Wg, g, 2048, 48, 2048);
  sigmoid_k<<<384, blk, 0, stream>>>(g, 98304);
  rope_inplace<<<8192, blk, 0, stream>>>(q);
  rope_inplace<<<8192, blk, 0, stream>>>(k);
  block_mean<<<256, blk, 0, stream>>>(k, kc);
  block_mean<<<256, blk, 0, stream>>>(v, vc);
  cmp_sel<<<128, blk, 0, stream>>>(q, kc, pc, sel);
  attn_fused<<<dim3(64, 16, 2), blk, 0, stream>>>(q, k, v, vc, pc, sel, g, o);
  gemm_f32<<<dim3(32, 32), blk, 0, stream>>>(o, Wo, out, 2048, 2048, 2048);
}

// Round 2
// 902.366 us; speedup vs baseline: 1.9869x; 1.9869x over previous
//
#include <hip/hip_runtime.h>
#include <hip/hip_bf16.h>

// NSA forward: B=2, N=1024, D=2048, H=16, HD=128, BS=64, SEL=8, WIN=64
#define HN   16
#define HDIM 128
#define NSEQ 1024
#define NBLK 16
#define BSZ  64
#define SCALE 0.08838834764831845f
#define QKV_STR 6144   // row stride of fused qkv buffer (bf16)
#define KOFS 2048
#define VOFS 4096

typedef __attribute__((ext_vector_type(8))) short bfrag;   // 8 bf16 (4 VGPRs)
typedef __attribute__((ext_vector_type(4))) float facc;    // MFMA accumulator

__device__ __forceinline__ float bf2f(short s) {
  union { unsigned u; float f; } cv;
  cv.u = ((unsigned)(unsigned short)s) << 16;
  return cv.f;
}
__device__ __forceinline__ short f2bf(float f) {
  unsigned u = __float_as_uint(f);
  u = (u + 0x7fff + ((u >> 16) & 1)) >> 16;  // RNE
  return (short)u;
}

#define ASYNC16(gp, lp)                                                    \
  __builtin_amdgcn_global_load_lds(                                        \
      (const __attribute__((address_space(1))) void*)(gp),                 \
      (__attribute__((address_space(3))) void*)(lp), 16, 0, 0)

// ------------------------------------------------------------------
// fp32 -> bf16 cast, 8 elems/thread
// ------------------------------------------------------------------
__global__ __launch_bounds__(256) void cast_bf16(const float* __restrict__ src,
                                                 short* __restrict__ dst, int n8) {
  int i = blockIdx.x * 256 + threadIdx.x;
  if (i < n8) {
    const float4 a = ((const float4*)src)[2 * i];
    const float4 b = ((const float4*)src)[2 * i + 1];
    bfrag o;
    o[0] = f2bf(a.x); o[1] = f2bf(a.y); o[2] = f2bf(a.z); o[3] = f2bf(a.w);
    o[4] = f2bf(b.x); o[5] = f2bf(b.y); o[6] = f2bf(b.z); o[7] = f2bf(b.w);
    ((bfrag*)dst)[i] = o;
  }
}

// ------------------------------------------------------------------
// fp32 [rows][cols] -> bf16 transpose [cols][rows], dst row offset dofs
// ------------------------------------------------------------------
__global__ __launch_bounds__(256) void transpose_cast(const float* __restrict__ src,
                                                      short* __restrict__ dst,
                                                      int rows, int cols, int dofs) {
  __shared__ float tile[32][33];
  const int bx = blockIdx.x * 32;  // src col
  const int by = blockIdx.y * 32;  // src row
  const int tx = threadIdx.x & 31, ty = threadIdx.x >> 5;
#pragma unroll
  for (int i = 0; i < 4; ++i)
    tile[ty + 8 * i][tx] = src[(size_t)(by + ty + 8 * i) * cols + bx + tx];
  __syncthreads();
#pragma unroll
  for (int i = 0; i < 4; ++i)
    dst[(size_t)(dofs + bx + ty + 8 * i) * rows + by + tx] = f2bf(tile[tx][ty + 8 * i]);
}

// ------------------------------------------------------------------
// bf16 MFMA GEMM, m97 structure: C[M][N] = A[M][K] * Bt[N][K]^T
// 128x128 tile, BK=32, 4 waves, global_load_lds(16B), 16 MFMA/K-step.
// ------------------------------------------------------------------
__device__ __forceinline__ void store_c(float* p, float v) { *p = v; }
__device__ __forceinline__ void store_c(short* p, float v) { *p = f2bf(v); }

template <typename OT>
__global__ __launch_bounds__(256) void gemm_bf16_bt(const short* __restrict__ A,
                                                    const short* __restrict__ Bt,
                                                    OT* __restrict__ C,
                                                    int M, int N, int K) {
  __shared__ short As[128 * 32];
  __shared__ short Bs[128 * 32];
  const int t = threadIdx.x;
  const int l = t & 63, w = t >> 6;
  const int wr = w >> 1, wc = w & 1;
  const int row0 = blockIdx.y * 128, col0 = blockIdx.x * 128;
  facc acc[4][4] = {};

  const int sr = t >> 2;         // staging row 0..63
  const int sk = (t & 3) * 8;    // staging k-offset (shorts)
  const short* Ag0 = A + (size_t)(row0 + sr) * K + sk;
  const short* Ag1 = Ag0 + (size_t)64 * K;
  const short* Bg0 = Bt + (size_t)(col0 + sr) * K + sk;
  const short* Bg1 = Bg0 + (size_t)64 * K;
  short* la = As + t * 8;
  short* lb = Bs + t * 8;

  const int lm = l & 15;
  const int lk = (l >> 4) * 8;

  for (int k0 = 0; k0 < K; k0 += 32) {
    ASYNC16(Ag0 + k0, la);
    ASYNC16(Ag1 + k0, la + 2048);
    ASYNC16(Bg0 + k0, lb);
    ASYNC16(Bg1 + k0, lb + 2048);
    __syncthreads();
    bfrag af[4], bf[4];
#pragma unroll
    for (int i = 0; i < 4; ++i)
      af[i] = *(const bfrag*)&As[(wr * 64 + i * 16 + lm) * 32 + lk];
#pragma unroll
    for (int j = 0; j < 4; ++j)
      bf[j] = *(const bfrag*)&Bs[(wc * 64 + j * 16 + lm) * 32 + lk];
#pragma unroll
    for (int i = 0; i < 4; ++i)
#pragma unroll
      for (int j = 0; j < 4; ++j)
        acc[i][j] = __builtin_amdgcn_mfma_f32_16x16x32_bf16(af[i], bf[j], acc[i][j], 0, 0, 0);
    __syncthreads();
  }

  const int orow = row0 + wr * 64 + (l >> 4) * 4;
  const int ocol = col0 + wc * 64 + lm;
#pragma unroll
  for (int i = 0; i < 4; ++i)
#pragma unroll
    for (int j = 0; j < 4; ++j)
#pragma unroll
      for (int rr = 0; rr < 4; ++rr)
        store_c(&C[(size_t)(orow + i * 16 + rr) * N + ocol + j * 16], acc[i][j][rr]);
}

// ------------------------------------------------------------------
// fp32 GEMM (kept for the tiny gate projection x @ Wg)
// ------------------------------------------------------------------
__global__ __launch_bounds__(256) void gemm_f32(const float* __restrict__ A,
                                                const float* __restrict__ B,
                                                float* __restrict__ C,
                                                int M, int N, int K) {
  __shared__ float As[16][68];
  __shared__ float Bs[16][68];
  const int t  = threadIdx.x;
  const int tx = t & 15, ty = t >> 4;
  const int row0 = blockIdx.y * 64;
  const int col0 = blockIdx.x * 64;
  float acc[4][4] = {{0.f, 0.f, 0.f, 0.f}};
  const int kkA = t & 15, rA = t >> 4;
  const int cB  = t & 63, kB = t >> 6;
  for (int k0 = 0; k0 < K; k0 += 16) {
#pragma unroll
    for (int j = 0; j < 4; ++j) {
      int rr = rA + 16 * j;
      As[kkA][rr] = A[(size_t)(row0 + rr) * K + (k0 + kkA)];
    }
#pragma unroll
    for (int j = 0; j < 4; ++j) {
      int kk2 = kB + 4 * j;
      int gc  = col0 + cB;
      Bs[kk2][cB] = (gc < N) ? B[(size_t)(k0 + kk2) * N + gc] : 0.f;
    }
    __syncthreads();
#pragma unroll
    for (int kq = 0; kq < 16; ++kq) {
      const float4 av = *(const float4*)&As[kq][ty * 4];
      const float4 bv = *(const float4*)&Bs[kq][tx * 4];
      const float a[4] = {av.x, av.y, av.z, av.w};
      const float b[4] = {bv.x, bv.y, bv.z, bv.w};
#pragma unroll
      for (int i = 0; i < 4; ++i)
#pragma unroll
        for (int jj = 0; jj < 4; ++jj) acc[i][jj] += a[i] * b[jj];
    }
    __syncthreads();
  }
#pragma unroll
  for (int i = 0; i < 4; ++i) {
    const int row = row0 + ty * 4 + i;
#pragma unroll
    for (int jj = 0; jj < 4; ++jj) {
      const int col = col0 + tx * 4 + jj;
      if (col < N) C[(size_t)row * N + col] = acc[i][jj];
    }
  }
}

__global__ __launch_bounds__(256) void sigmoid_k(float* __restrict__ p, int n) {
  int i = blockIdx.x * 256 + threadIdx.x;
  if (i < n) p[i] = 1.0f / (1.0f + __expf(-p[i]));
}

// ------------------------------------------------------------------
// RoPE in place on bf16 qkv buffer slice (q or k), row stride QKV_STR
// ------------------------------------------------------------------
__global__ __launch_bounds__(256) void rope_inplace(short* __restrict__ p) {
  int i = blockIdx.x * 256 + threadIdx.x;  // B*N*H*64 = 2097152
  int d = i & 63;
  int h = (i >> 6) & 15;
  int n = (i >> 10) & 1023;
  int b = i >> 20;
  short* base = p + (size_t)(b * NSEQ + n) * QKV_STR + h * HDIM + d;
  float inv = expf(-(float)d * (9.210340371976184f / 64.0f));
  float th = (float)n * inv;
  float sn, cs;
  sincosf(th, &sn, &cs);
  float t1 = bf2f(base[0]), t2 = bf2f(base[64]);
  base[0]  = f2bf(t1 * cs - t2 * sn);
  base[64] = f2bf(t1 * sn + t2 * cs);
}

// ------------------------------------------------------------------
// Block mean over bf16 src slice -> f32 dst [b][m][h][d]
// ------------------------------------------------------------------
__global__ __launch_bounds__(256) void block_mean(const short* __restrict__ src,
                                                  float* __restrict__ dst) {
  int i = blockIdx.x * 256 + threadIdx.x;  // 65536
  int d = i & 127;
  int h = (i >> 7) & 15;
  int m = (i >> 11) & 15;
  int b = i >> 15;
  const short* p = src + (size_t)(b * NSEQ + m * BSZ) * QKV_STR + h * HDIM + d;
  float acc = 0.f;
#pragma unroll 8
  for (int j = 0; j < 64; ++j) acc += bf2f(p[(size_t)j * QKV_STR]);
  dst[i] = acc * (1.0f / 64.0f);
}

// ------------------------------------------------------------------
// Compressed attention probs + top-8 selection (q bf16, kc f32)
// ------------------------------------------------------------------
__global__ __launch_bounds__(256) void cmp_sel(const short* __restrict__ qkv,
                                               const float* __restrict__ kc,
                                               float* __restrict__ pc,
                                               int* __restrict__ sel) {
  int i = blockIdx.x * 256 + threadIdx.x;  // B*H*N = 32768
  int n = i & 1023;
  int h = (i >> 10) & 15;
  int b = i >> 14;
  const short* qp = qkv + (size_t)(b * NSEQ + n) * QKV_STR + h * HDIM;
  float qf[HDIM];
#pragma unroll
  for (int d0 = 0; d0 < HDIM; d0 += 8) {
    bfrag qv = *(const bfrag*)&qp[d0];
#pragma unroll
    for (int dd = 0; dd < 8; ++dd) qf[d0 + dd] = bf2f(qv[dd]);
  }
  const int nv = (n + 1) >> 6;
  float s[NBLK];
  float mx = -1e30f;
  for (int m = 0; m < nv; ++m) {
    const float* kp = kc + ((size_t)((b * NBLK + m) * HN + h) << 7);
    float dot = 0.f;
    for (int d = 0; d < HDIM; d += 4) {
      const float4 kv = *(const float4*)&kp[d];
      dot += qf[d] * kv.x + qf[d + 1] * kv.y + qf[d + 2] * kv.z + qf[d + 3] * kv.w;
    }
    s[m] = dot * SCALE;
    mx = fmaxf(mx, s[m]);
  }
  float den = 0.f;
  for (int m = 0; m < nv; ++m) { s[m] = __expf(s[m] - mx); den += s[m]; }
  const float rden = (nv > 0) ? 1.0f / den : 0.f;
  float p[NBLK];
#pragma unroll
  for (int m = 0; m < NBLK; ++m) p[m] = (m < nv) ? s[m] * rden : 0.f;
  float* pout = pc + (size_t)i * NBLK;
#pragma unroll
  for (int m = 0; m < NBLK; ++m) pout[m] = p[m];
  p[n >> 6] += 2.0f;
  int mask = 0;
#pragma unroll
  for (int ss = 0; ss < 8; ++ss) {
    int best = 0;
    float bv = -1e30f;
#pragma unroll
    for (int m = 0; m < NBLK; ++m)
      if (p[m] > bv) { bv = p[m]; best = m; }
    mask |= 1 << best;
    p[best] = -1e30f;
  }
  sel[i] = mask;
}

// ------------------------------------------------------------------
// Fused slc + swa + cmp-output attention. bf16 q/k/v staged in LDS,
// fp32 math, bf16 output (row = b*1024+n, col = h*128+d).
// ------------------------------------------------------------------
__global__ __launch_bounds__(256) void attn_fused(
    const short* __restrict__ qkv, const float* __restrict__ vc,
    const float* __restrict__ pc, const int* __restrict__ sel,
    const float* __restrict__ g, short* __restrict__ o) {
  const int rt = blockIdx.x, h = blockIdx.y, b = blockIdx.z;
  const int t  = threadIdx.x;
  const int r  = t >> 4;   // row in tile (0..15)
  const int c8 = t & 15;   // dim chunk: dims [c8*8, c8*8+8)
  const int nbase = rt * 16;

  __shared__ short q_s[16][128];
  __shared__ short kv_s[64][136];
  __shared__ float e_s[16][66];
  __shared__ float p_s[16][16];
  __shared__ int   sel_s[16];

  {
    int rr = t >> 4, d8 = (t & 15) * 8;
    *(bfrag*)&q_s[rr][d8] =
        *(const bfrag*)&qkv[(size_t)(b * NSEQ + nbase + rr) * QKV_STR + h * HDIM + d8];
  }
  p_s[r][c8] = pc[((size_t)((b * HN + h) * NSEQ) + nbase + r) * NBLK + c8];
  if (t < 16) sel_s[t] = sel[(size_t)(b * HN + h) * NSEQ + nbase + t];
  __syncthreads();

  const int n = nbase + r;
  float accs[8] = {0.f, 0.f, 0.f, 0.f, 0.f, 0.f, 0.f, 0.f};
  float accw[8] = {0.f, 0.f, 0.f, 0.f, 0.f, 0.f, 0.f, 0.f};
  float dens = 0.f, denw = 0.f;
  const int ntiles = (nbase + 15) / 64 + 1;

  for (int ct = 0; ct < ntiles; ++ct) {
    const int cbase = ct * 64;
    int f = 0;
#pragma unroll
    for (int rr = 0; rr < 16; ++rr) {
      const int nn = nbase + rr;
      f |= (cbase <= nn) &&
           ((((sel_s[rr] >> ct) & 1) != 0) || (cbase + 63 >= nn - 64));
    }
    if (!f) continue;

    // stage K tile (bf16)
#pragma unroll
    for (int it = 0; it < 4; ++it) {
      int idx = t + 256 * it;
      int j = idx >> 4, d8 = (idx & 15) * 8;
      *(bfrag*)&kv_s[j][d8] =
          *(const bfrag*)&qkv[(size_t)(b * NSEQ + cbase + j) * QKV_STR + KOFS + h * HDIM + d8];
    }
    __syncthreads();

    // scores: thread (r, c8) covers cols c8 + 16*pp
    float sc[4] = {0.f, 0.f, 0.f, 0.f};
    for (int d0 = 0; d0 < 128; d0 += 8) {
      bfrag qv = *(const bfrag*)&q_s[r][d0];
      float qf[8];
#pragma unroll
      for (int dd = 0; dd < 8; ++dd) qf[dd] = bf2f(qv[dd]);
#pragma unroll
      for (int pp = 0; pp < 4; ++pp) {
        bfrag kb = *(const bfrag*)&kv_s[c8 + 16 * pp][d0];
#pragma unroll
        for (int dd = 0; dd < 8; ++dd) sc[pp] += qf[dd] * bf2f(kb[dd]);
      }
    }
#pragma unroll
    for (int pp = 0; pp < 4; ++pp)
      e_s[r][c8 + 16 * pp] = __expf(sc[pp] * SCALE);
    __syncthreads();

    // stage V tile (reuse kv_s)
#pragma unroll
    for (int it = 0; it < 4; ++it) {
      int idx = t + 256 * it;
      int j = idx >> 4, d8 = (idx & 15) * 8;
      *(bfrag*)&kv_s[j][d8] =
          *(const bfrag*)&qkv[(size_t)(b * NSEQ + cbase + j) * QKV_STR + VOFS + h * HDIM + d8];
    }
    __syncthreads();

    const bool slc_on = ((sel_s[r] >> ct) & 1) != 0;
    const int jmax = min(64, n - cbase + 1);
    for (int j = 0; j < jmax; ++j) {
      const float e = e_s[r][j];
      bfrag vs = *(const bfrag*)&kv_s[j][c8 * 8];
      float vv[8];
#pragma unroll
      for (int ii = 0; ii < 8; ++ii) vv[ii] = bf2f(vs[ii]);
      if (slc_on) {
        dens += e;
#pragma unroll
        for (int ii = 0; ii < 8; ++ii) accs[ii] += e * vv[ii];
      }
      if (n - (cbase + j) <= 64) {
        denw += e;
#pragma unroll
        for (int ii = 0; ii < 8; ++ii) accw[ii] += e * vv[ii];
      }
    }
    __syncthreads();
  }

  // compressed-branch output
  float accc[8] = {0.f, 0.f, 0.f, 0.f, 0.f, 0.f, 0.f, 0.f};
#pragma unroll
  for (int m = 0; m < NBLK; ++m) {
    const float pcm = p_s[r][m];
    if (pcm != 0.f) {
      const float* vp = vc + ((size_t)((b * NBLK + m) * HN + h) << 7) + c8 * 8;
      const float4 v0 = *(const float4*)&vp[0];
      const float4 v1 = *(const float4*)&vp[4];
      accc[0] += pcm * v0.x; accc[1] += pcm * v0.y;
      accc[2] += pcm * v0.z; accc[3] += pcm * v0.w;
      accc[4] += pcm * v1.x; accc[5] += pcm * v1.y;
      accc[6] += pcm * v1.z; accc[7] += pcm * v1.w;
    }
  }

  const size_t grow = (size_t)(b * NSEQ + n) * 48;
  const float gc = g[grow + h];
  const float gs = g[grow + 16 + h];
  const float gw = g[grow + 32 + h];
  const float is = 1.0f / dens;
  const float iw = 1.0f / denw;
  bfrag ov;
#pragma unroll
  for (int ii = 0; ii < 8; ++ii)
    ov[ii] = f2bf(gc * accc[ii] + gs * accs[ii] * is + gw * accw[ii] * iw);
  *(bfrag*)&o[(size_t)(b * NSEQ + n) * 2048 + h * HDIM + c8 * 8] = ov;
}

// ------------------------------------------------------------------
extern "C" void kernel_launch(void* const* d_in, const int* in_sizes, int n_in,
                              void* d_out, int out_size, void* d_ws, size_t ws_size,
                              hipStream_t stream) {
  const float* x  = (const float*)d_in[0];
  const float* Wq = (const float*)d_in[1];
  const float* Wk = (const float*)d_in[2];
  const float* Wv = (const float*)d_in[3];
  const float* Wg = (const float*)d_in[4];
  const float* Wo = (const float*)d_in[5];
  float* out = (float*)d_out;

  char* w = (char*)d_ws;
  short* x_bf = (short*)w;            // 2048*2048 bf16 = 8.4 MB (reused as o_bf)
  short* o_bf = x_bf;
  w += (size_t)2048 * 2048 * 2;
  short* w_t  = (short*)w;            // 6144*2048 bf16 = 25.2 MB (reused as Wo_t)
  w += (size_t)6144 * 2048 * 2;
  short* qkv  = (short*)w;            // 2048*6144 bf16 = 25.2 MB
  w += (size_t)2048 * 6144 * 2;
  float* g    = (float*)w; w += (size_t)98304 * 4;
  float* kc   = (float*)w; w += (size_t)65536 * 4;
  float* vc   = (float*)w; w += (size_t)65536 * 4;
  float* pc   = (float*)w; w += (size_t)524288 * 4;
  int*   sel  = (int*)w;   w += (size_t)32768 * 4;

  const dim3 blk(256);
  cast_bf16<<<2048, blk, 0, stream>>>(x, x_bf, 524288);
  transpose_cast<<<dim3(64, 64), blk, 0, stream>>>(Wq, w_t, 2048, 2048, 0);
  transpose_cast<<<dim3(64, 64), blk, 0, stream>>>(Wk, w_t, 2048, 2048, 2048);
  transpose_cast<<<dim3(64, 64), blk, 0, stream>>>(Wv, w_t, 2048, 2048, 4096);
  gemm_bf16_bt<short><<<dim3(48, 16), blk, 0, stream>>>(x_bf, w_t, qkv, 2048, 6144, 2048);
  gemm_f32<<<dim3(1, 32), blk, 0, stream>>>(x, Wg, g, 2048, 48, 2048);
  sigmoid_k<<<384, blk, 0, stream>>>(g, 98304);
  rope_inplace<<<8192, blk, 0, stream>>>(qkv);          // q slice
  rope_inplace<<<8192, blk, 0, stream>>>(qkv + KOFS);   // k slice
  block_mean<<<256, blk, 0, stream>>>(qkv + KOFS, kc);
  block_mean<<<256, blk, 0, stream>>>(qkv + VOFS, vc);
  cmp_sel<<<128, blk, 0, stream>>>(qkv, kc, pc, sel);
  transpose_cast<<<dim3(64, 64), blk, 0, stream>>>(Wo, w_t, 2048, 2048, 0);  // Wo^T reuses w_t
  attn_fused<<<dim3(64, 16, 2), blk, 0, stream>>>(qkv, vc, pc, sel, g, o_bf);
  gemm_bf16_bt<float><<<dim3(16, 16), blk, 0, stream>>>(o_bf, w_t, out, 2048, 2048, 2048);
}

// Round 3
// 611.820 us; speedup vs baseline: 2.9305x; 1.4749x over previous
//
#include <hip/hip_runtime.h>
#include <hip/hip_bf16.h>

// NSA forward: B=2, N=1024, D=2048, H=16, HD=128, BS=64, SEL=8, WIN=64
#define HN   16
#define HDIM 128
#define NSEQ 1024
#define NBLK 16
#define BSZ  64
#define SCALE 0.08838834764831845f
#define QKV_STR 6144   // row stride of fused qkv buffer (bf16)
#define KOFS 2048
#define VOFS 4096

typedef __attribute__((ext_vector_type(8))) short bfrag;   // 8 bf16 (4 VGPRs)
typedef __attribute__((ext_vector_type(4))) float facc;    // MFMA accumulator

__device__ __forceinline__ float bf2f(short s) {
  union { unsigned u; float f; } cv;
  cv.u = ((unsigned)(unsigned short)s) << 16;
  return cv.f;
}
__device__ __forceinline__ short f2bf(float f) {
  unsigned u = __float_as_uint(f);
  u = (u + 0x7fff + ((u >> 16) & 1)) >> 16;  // RNE
  return (short)u;
}

#define ASYNC16(gp, lp)                                                    \
  __builtin_amdgcn_global_load_lds(                                        \
      (const __attribute__((address_space(1))) void*)(gp),                 \
      (__attribute__((address_space(3))) void*)(lp), 16, 0, 0)

#define MFMA16(a, b, c) __builtin_amdgcn_mfma_f32_16x16x32_bf16(a, b, c, 0, 0, 0)

// ------------------------------------------------------------------
// fp32 -> bf16 cast, 8 elems/thread
// ------------------------------------------------------------------
__global__ __launch_bounds__(256) void cast_bf16(const float* __restrict__ src,
                                                 short* __restrict__ dst, int n8) {
  int i = blockIdx.x * 256 + threadIdx.x;
  if (i < n8) {
    const float4 a = ((const float4*)src)[2 * i];
    const float4 b = ((const float4*)src)[2 * i + 1];
    bfrag o;
    o[0] = f2bf(a.x); o[1] = f2bf(a.y); o[2] = f2bf(a.z); o[3] = f2bf(a.w);
    o[4] = f2bf(b.x); o[5] = f2bf(b.y); o[6] = f2bf(b.z); o[7] = f2bf(b.w);
    ((bfrag*)dst)[i] = o;
  }
}

// ------------------------------------------------------------------
// fp32 [rows][cols] -> bf16 transpose [cols][rows], dst row offset dofs
// ------------------------------------------------------------------
__global__ __launch_bounds__(256) void transpose_cast(const float* __restrict__ src,
                                                      short* __restrict__ dst,
                                                      int rows, int cols, int dofs) {
  __shared__ float tile[32][33];
  const int bx = blockIdx.x * 32;  // src col
  const int by = blockIdx.y * 32;  // src row
  const int tx = threadIdx.x & 31, ty = threadIdx.x >> 5;
#pragma unroll
  for (int i = 0; i < 4; ++i)
    tile[ty + 8 * i][tx] = src[(size_t)(by + ty + 8 * i) * cols + bx + tx];
  __syncthreads();
#pragma unroll
  for (int i = 0; i < 4; ++i)
    dst[(size_t)(dofs + bx + ty + 8 * i) * rows + by + tx] = f2bf(tile[tx][ty + 8 * i]);
}

// ------------------------------------------------------------------
// bf16 MFMA GEMM, m97 structure: C[M][N] = A[M][K] * Bt[N][K]^T
// ------------------------------------------------------------------
__device__ __forceinline__ void store_c(float* p, float v) { *p = v; }
__device__ __forceinline__ void store_c(short* p, float v) { *p = f2bf(v); }

template <typename OT>
__global__ __launch_bounds__(256) void gemm_bf16_bt(const short* __restrict__ A,
                                                    const short* __restrict__ Bt,
                                                    OT* __restrict__ C,
                                                    int M, int N, int K) {
  __shared__ short As[128 * 32];
  __shared__ short Bs[128 * 32];
  const int t = threadIdx.x;
  const int l = t & 63, w = t >> 6;
  const int wr = w >> 1, wc = w & 1;
  const int row0 = blockIdx.y * 128, col0 = blockIdx.x * 128;
  facc acc[4][4] = {};

  const int sr = t >> 2;
  const int sk = (t & 3) * 8;
  const short* Ag0 = A + (size_t)(row0 + sr) * K + sk;
  const short* Ag1 = Ag0 + (size_t)64 * K;
  const short* Bg0 = Bt + (size_t)(col0 + sr) * K + sk;
  const short* Bg1 = Bg0 + (size_t)64 * K;
  short* la = As + t * 8;
  short* lb = Bs + t * 8;

  const int lm = l & 15;
  const int lk = (l >> 4) * 8;

  for (int k0 = 0; k0 < K; k0 += 32) {
    ASYNC16(Ag0 + k0, la);
    ASYNC16(Ag1 + k0, la + 2048);
    ASYNC16(Bg0 + k0, lb);
    ASYNC16(Bg1 + k0, lb + 2048);
    __syncthreads();
    bfrag af[4], bf[4];
#pragma unroll
    for (int i = 0; i < 4; ++i)
      af[i] = *(const bfrag*)&As[(wr * 64 + i * 16 + lm) * 32 + lk];
#pragma unroll
    for (int j = 0; j < 4; ++j)
      bf[j] = *(const bfrag*)&Bs[(wc * 64 + j * 16 + lm) * 32 + lk];
#pragma unroll
    for (int i = 0; i < 4; ++i)
#pragma unroll
      for (int j = 0; j < 4; ++j)
        acc[i][j] = MFMA16(af[i], bf[j], acc[i][j]);
    __syncthreads();
  }

  const int orow = row0 + wr * 64 + (l >> 4) * 4;
  const int ocol = col0 + wc * 64 + lm;
#pragma unroll
  for (int i = 0; i < 4; ++i)
#pragma unroll
    for (int j = 0; j < 4; ++j)
#pragma unroll
      for (int rr = 0; rr < 4; ++rr)
        store_c(&C[(size_t)(orow + i * 16 + rr) * N + ocol + j * 16], acc[i][j][rr]);
}

// ------------------------------------------------------------------
// fp32 GEMM (gate projection x @ Wg only)
// ------------------------------------------------------------------
__global__ __launch_bounds__(256) void gemm_f32(const float* __restrict__ A,
                                                const float* __restrict__ B,
                                                float* __restrict__ C,
                                                int M, int N, int K) {
  __shared__ float As[16][68];
  __shared__ float Bs[16][68];
  const int t  = threadIdx.x;
  const int tx = t & 15, ty = t >> 4;
  const int row0 = blockIdx.y * 64;
  const int col0 = blockIdx.x * 64;
  float acc[4][4] = {{0.f, 0.f, 0.f, 0.f}};
  const int kkA = t & 15, rA = t >> 4;
  const int cB  = t & 63, kB = t >> 6;
  for (int k0 = 0; k0 < K; k0 += 16) {
#pragma unroll
    for (int j = 0; j < 4; ++j) {
      int rr = rA + 16 * j;
      As[kkA][rr] = A[(size_t)(row0 + rr) * K + (k0 + kkA)];
    }
#pragma unroll
    for (int j = 0; j < 4; ++j) {
      int kk2 = kB + 4 * j;
      int gc  = col0 + cB;
      Bs[kk2][cB] = (gc < N) ? B[(size_t)(k0 + kk2) * N + gc] : 0.f;
    }
    __syncthreads();
#pragma unroll
    for (int kq = 0; kq < 16; ++kq) {
      const float4 av = *(const float4*)&As[kq][ty * 4];
      const float4 bv = *(const float4*)&Bs[kq][tx * 4];
      const float a[4] = {av.x, av.y, av.z, av.w};
      const float b[4] = {bv.x, bv.y, bv.z, bv.w};
#pragma unroll
      for (int i = 0; i < 4; ++i)
#pragma unroll
        for (int jj = 0; jj < 4; ++jj) acc[i][jj] += a[i] * b[jj];
    }
    __syncthreads();
  }
#pragma unroll
  for (int i = 0; i < 4; ++i) {
    const int row = row0 + ty * 4 + i;
#pragma unroll
    for (int jj = 0; jj < 4; ++jj) {
      const int col = col0 + tx * 4 + jj;
      if (col < N) C[(size_t)row * N + col] = acc[i][jj];
    }
  }
}

__global__ __launch_bounds__(256) void sigmoid_k(float* __restrict__ p, int n) {
  int i = blockIdx.x * 256 + threadIdx.x;
  if (i < n) p[i] = 1.0f / (1.0f + __expf(-p[i]));
}

// ------------------------------------------------------------------
// RoPE in place on bf16 qkv slice, row stride QKV_STR
// ------------------------------------------------------------------
__global__ __launch_bounds__(256) void rope_inplace(short* __restrict__ p) {
  int i = blockIdx.x * 256 + threadIdx.x;  // 2097152
  int d = i & 63;
  int h = (i >> 6) & 15;
  int n = (i >> 10) & 1023;
  int b = i >> 20;
  short* base = p + (size_t)(b * NSEQ + n) * QKV_STR + h * HDIM + d;
  float inv = expf(-(float)d * (9.210340371976184f / 64.0f));
  float th = (float)n * inv;
  float sn, cs;
  sincosf(th, &sn, &cs);
  float t1 = bf2f(base[0]), t2 = bf2f(base[64]);
  base[0]  = f2bf(t1 * cs - t2 * sn);
  base[64] = f2bf(t1 * sn + t2 * cs);
}

// ------------------------------------------------------------------
// Block mean (roped K) -> f32 kc [b][m][h][d]
// ------------------------------------------------------------------
__global__ __launch_bounds__(256) void block_mean(const short* __restrict__ src,
                                                  float* __restrict__ dst) {
  int i = blockIdx.x * 256 + threadIdx.x;  // 65536
  int d = i & 127;
  int h = (i >> 7) & 15;
  int m = (i >> 11) & 15;
  int b = i >> 15;
  const short* p = src + (size_t)(b * NSEQ + m * BSZ) * QKV_STR + h * HDIM + d;
  float acc = 0.f;
#pragma unroll 8
  for (int j = 0; j < 64; ++j) acc += bf2f(p[(size_t)j * QKV_STR]);
  dst[i] = acc * (1.0f / 64.0f);
}

// ------------------------------------------------------------------
// Block mean (V) -> bf16 vcT [b][h][d][m]  (B-operand layout for cmp MFMA)
// ------------------------------------------------------------------
__global__ __launch_bounds__(256) void block_mean_vt(const short* __restrict__ src,
                                                     short* __restrict__ vct) {
  int i = blockIdx.x * 256 + threadIdx.x;  // 65536
  int d = i & 127;
  int h = (i >> 7) & 15;
  int m = (i >> 11) & 15;
  int b = i >> 15;
  const short* p = src + (size_t)(b * NSEQ + m * BSZ) * QKV_STR + h * HDIM + d;
  float acc = 0.f;
#pragma unroll 8
  for (int j = 0; j < 64; ++j) acc += bf2f(p[(size_t)j * QKV_STR]);
  vct[(((size_t)(b * HN + h) * 128) + d) * 16 + m] = f2bf(acc * (1.0f / 64.0f));
}

// ------------------------------------------------------------------
// V transpose: qkv V slice -> vt[b][h][d][n] bf16
// ------------------------------------------------------------------
__global__ __launch_bounds__(256) void v_transpose(const short* __restrict__ qkv,
                                                   short* __restrict__ vt) {
  __shared__ short tile[64][136];
  const int n0 = blockIdx.x * 64;
  const int h = blockIdx.y, b = blockIdx.z;
  const int t = threadIdx.x;
#pragma unroll
  for (int it = 0; it < 4; ++it) {
    int idx = t + 256 * it;           // 0..1023
    int row = idx >> 4, ch = idx & 15;
    *(bfrag*)&tile[row][ch * 8] =
        *(const bfrag*)&qkv[(size_t)(b * NSEQ + n0 + row) * QKV_STR + VOFS + h * HDIM + ch * 8];
  }
  __syncthreads();
#pragma unroll
  for (int it = 0; it < 4; ++it) {
    int idx = t + 256 * it;           // 0..1023
    int d = idx >> 3, ch = idx & 7;
    bfrag tv;
#pragma unroll
    for (int j = 0; j < 8; ++j) tv[j] = tile[ch * 8 + j][d];
    *(bfrag*)&vt[(((size_t)(b * HN + h) * 128) + d) * 1024 + n0 + ch * 8] = tv;
  }
}

// ------------------------------------------------------------------
// Compressed probs (bf16 pc [b][h][n][16]) + top-8 selection bitmask
// ------------------------------------------------------------------
__global__ __launch_bounds__(256) void cmp_sel(const short* __restrict__ qkv,
                                               const float* __restrict__ kc,
                                               short* __restrict__ pc,
                                               int* __restrict__ sel) {
  int i = blockIdx.x * 256 + threadIdx.x;  // B*H*N = 32768
  int n = i & 1023;
  int h = (i >> 10) & 15;
  int b = i >> 14;
  const short* qp = qkv + (size_t)(b * NSEQ + n) * QKV_STR + h * HDIM;
  float qf[HDIM];
#pragma unroll
  for (int d0 = 0; d0 < HDIM; d0 += 8) {
    bfrag qv = *(const bfrag*)&qp[d0];
#pragma unroll
    for (int dd = 0; dd < 8; ++dd) qf[d0 + dd] = bf2f(qv[dd]);
  }
  const int nv = (n + 1) >> 6;
  float s[NBLK];
  float mx = -1e30f;
  for (int m = 0; m < nv; ++m) {
    const float* kp = kc + ((size_t)((b * NBLK + m) * HN + h) << 7);
    float dot = 0.f;
    for (int d = 0; d < HDIM; d += 4) {
      const float4 kv = *(const float4*)&kp[d];
      dot += qf[d] * kv.x + qf[d + 1] * kv.y + qf[d + 2] * kv.z + qf[d + 3] * kv.w;
    }
    s[m] = dot * SCALE;
    mx = fmaxf(mx, s[m]);
  }
  float den = 0.f;
  for (int m = 0; m < nv; ++m) { s[m] = __expf(s[m] - mx); den += s[m]; }
  const float rden = (nv > 0) ? 1.0f / den : 0.f;
  float p[NBLK];
#pragma unroll
  for (int m = 0; m < NBLK; ++m) p[m] = (m < nv) ? s[m] * rden : 0.f;
  bfrag o0, o1;
#pragma unroll
  for (int m = 0; m < 8; ++m) { o0[m] = f2bf(p[m]); o1[m] = f2bf(p[m + 8]); }
  bfrag* pout = (bfrag*)(pc + (size_t)i * 16);
  pout[0] = o0; pout[1] = o1;
  p[n >> 6] += 2.0f;
  int mask = 0;
#pragma unroll
  for (int ss = 0; ss < 8; ++ss) {
    int best = 0;
    float bv = -1e30f;
#pragma unroll
    for (int m = 0; m < NBLK; ++m)
      if (p[m] > bv) { bv = p[m]; best = m; }
    mask |= 1 << best;
    p[best] = -1e30f;
  }
  sel[i] = mask;
}

// ------------------------------------------------------------------
// MFMA attention: one wave per (b, h, 16-row tile).
// slc + swa share QK^T/exp; separate masked P -> 2 PV passes.
// cmp branch = one more MFMA pass over pc/vcT. All normalization +
// gating fused in epilogue.
// ------------------------------------------------------------------
__global__ __launch_bounds__(64) void attn_mfma(
    const short* __restrict__ qkv, const short* __restrict__ vt,
    const short* __restrict__ vct, const short* __restrict__ pc,
    const int* __restrict__ sel, const float* __restrict__ g,
    short* __restrict__ o) {
  const int rt = blockIdx.x, h = blockIdx.y, b = blockIdx.z;
  const int l = threadIdx.x;
  const int lm = l & 15, hi = l >> 4;
  const int nbase = rt * 16;

  __shared__ short p_slc[1024];
  __shared__ short p_swa[1024];

  // Q A-fragments (row = lm, k = 32*ks + 8*hi + j)
  const short* qrow = qkv + (size_t)(b * NSEQ + nbase + lm) * QKV_STR + h * HDIM;
  bfrag qf[4];
#pragma unroll
  for (int ks = 0; ks < 4; ++ks) qf[ks] = *(const bfrag*)&qrow[32 * ks + 8 * hi];

  // selection bits
  int selrow = sel[(size_t)(b * HN + h) * NSEQ + nbase + lm];
  int uni = selrow;
#pragma unroll
  for (int m = 1; m < 16; m <<= 1) uni |= __shfl_xor(uni, m);
  int sel4[4];
#pragma unroll
  for (int rg = 0; rg < 4; ++rg) sel4[rg] = __shfl(selrow, 4 * hi + rg);

  const int thi = nbase >> 6;                      // last causal tile
  const int tlo = (nbase >= 64) ? ((nbase - 64) >> 6) : 0;
  const int wmask = (int)((2u << thi) - (1u << tlo));

  facc acc_slc[8] = {}, acc_swa[8] = {}, acc_cmp[8] = {};
  float ps_s[4] = {0.f, 0.f, 0.f, 0.f}, ps_w[4] = {0.f, 0.f, 0.f, 0.f};

  // ---- compressed branch: O_cmp = Pc[16x16] * Vc[16x128], K padded to 32
  {
    bfrag pa = {};
    if (hi < 2)
      pa = *(const bfrag*)&pc[((size_t)(b * HN + h) * NSEQ + nbase + lm) * 16 + 8 * hi];
#pragma unroll
    for (int df = 0; df < 8; ++df) {
      bfrag vb = {};
      if (hi < 2)
        vb = *(const bfrag*)&vct[(((size_t)(b * HN + h) * 128) + 16 * df + lm) * 16 + 8 * hi];
      acc_cmp[df] = MFMA16(pa, vb, acc_cmp[df]);
    }
  }

  // ---- main tile loop
  const short* kbase0 = qkv + (size_t)(b * NSEQ) * QKV_STR + KOFS + h * HDIM;
  const short* vtb0 = vt + ((size_t)(b * HN + h) * 128) * 1024;

  for (int ct = 0; ct <= thi; ++ct) {
    const bool do_s = (uni >> ct) & 1;
    const bool do_w = (wmask >> ct) & 1;
    if (!do_s && !do_w) continue;

    // QK^T (S[16 rows][64 cols] in 4 col-fragments)
    facc sacc[4] = {};
#pragma unroll
    for (int f = 0; f < 4; ++f) {
      const short* krow = kbase0 + (size_t)(ct * 64 + 16 * f + lm) * QKV_STR;
#pragma unroll
      for (int ks = 0; ks < 4; ++ks) {
        bfrag kb = *(const bfrag*)&krow[32 * ks + 8 * hi];
        sacc[f] = MFMA16(qf[ks], kb, sacc[f]);
      }
    }

    // exp + masks + partial sums + LDS P write (XOR-swizzled)
#pragma unroll
    for (int f = 0; f < 4; ++f) {
      const int col = ct * 64 + 16 * f + lm;
#pragma unroll
      for (int rg = 0; rg < 4; ++rg) {
        const int row = nbase + 4 * hi + rg;
        float e = __expf(sacc[f][rg] * SCALE);
        e = (col <= row) ? e : 0.f;
        float es = ((sel4[rg] >> ct) & 1) ? e : 0.f;
        float ew = (row - col <= 64) ? e : 0.f;
        ps_s[rg] += es;
        ps_w[rg] += ew;
        const int srow = 4 * hi + rg;
        const int sidx = (64 * srow + 16 * f + lm) ^ ((srow & 7) << 3);
        if (do_s) p_slc[sidx] = f2bf(es);
        if (do_w) p_swa[sidx] = f2bf(ew);
      }
    }
    __syncthreads();

    // PV for active branches (V B-frags from vt, shared)
    const short* vtb = vtb0 + ct * 64;
#pragma unroll
    for (int ks = 0; ks < 2; ++ks) {
      const int ridx = (64 * lm + 8 * hi + 32 * ks) ^ ((lm & 7) << 3);
      bfrag pas = {}, paw = {};
      if (do_s) pas = *(const bfrag*)&p_slc[ridx];
      if (do_w) paw = *(const bfrag*)&p_swa[ridx];
#pragma unroll
      for (int df = 0; df < 8; ++df) {
        bfrag vb = *(const bfrag*)&vtb[(size_t)(16 * df + lm) * 1024 + 32 * ks + 8 * hi];
        if (do_s) acc_slc[df] = MFMA16(pas, vb, acc_slc[df]);
        if (do_w) acc_swa[df] = MFMA16(paw, vb, acc_swa[df]);
      }
    }
    __syncthreads();
  }

  // ---- denominators: reduce across the 16 col-lanes
#pragma unroll
  for (int m = 1; m < 16; m <<= 1) {
#pragma unroll
    for (int rg = 0; rg < 4; ++rg) {
      ps_s[rg] += __shfl_xor(ps_s[rg], m);
      ps_w[rg] += __shfl_xor(ps_w[rg], m);
    }
  }

  float inv_s[4], inv_w[4], gcv[4], gsv[4], gwv[4];
#pragma unroll
  for (int rg = 0; rg < 4; ++rg) {
    inv_s[rg] = 1.0f / ps_s[rg];
    inv_w[rg] = 1.0f / ps_w[rg];
    const size_t grow = (size_t)(b * NSEQ + nbase + 4 * hi + rg) * 48;
    gcv[rg] = g[grow + h];
    gsv[rg] = g[grow + 16 + h];
    gwv[rg] = g[grow + 32 + h];
  }

  short* obase = o + (size_t)(b * NSEQ + nbase) * 2048 + h * HDIM;
#pragma unroll
  for (int df = 0; df < 8; ++df)
#pragma unroll
    for (int rg = 0; rg < 4; ++rg) {
      float val = gcv[rg] * acc_cmp[df][rg] +
                  gsv[rg] * acc_slc[df][rg] * inv_s[rg] +
                  gwv[rg] * acc_swa[df][rg] * inv_w[rg];
      obase[(size_t)(4 * hi + rg) * 2048 + 16 * df + lm] = f2bf(val);
    }
}

// ------------------------------------------------------------------
extern "C" void kernel_launch(void* const* d_in, const int* in_sizes, int n_in,
                              void* d_out, int out_size, void* d_ws, size_t ws_size,
                              hipStream_t stream) {
  const float* x  = (const float*)d_in[0];
  const float* Wq = (const float*)d_in[1];
  const float* Wk = (const float*)d_in[2];
  const float* Wv = (const float*)d_in[3];
  const float* Wg = (const float*)d_in[4];
  const float* Wo = (const float*)d_in[5];
  float* out = (float*)d_out;

  char* w = (char*)d_ws;
  short* x_bf = (short*)w;            // 8.4 MB (reused as o_bf after qkv gemm)
  short* o_bf = x_bf;
  w += (size_t)2048 * 2048 * 2;
  short* w_t  = (short*)w;            // 25.2 MB (reused for Wo^T)
  w += (size_t)6144 * 2048 * 2;
  short* qkv  = (short*)w;            // 25.2 MB
  w += (size_t)2048 * 6144 * 2;
  float* g    = (float*)w; w += (size_t)98304 * 4;
  float* kc   = (float*)w; w += (size_t)65536 * 4;
  short* vct  = (short*)w; w += (size_t)65536 * 2;
  short* pcb  = (short*)w; w += (size_t)524288 * 2;
  int*   sel  = (int*)w;   w += (size_t)32768 * 4;
  short* vt   = (short*)w; w += (size_t)4194304 * 2;   // 8.4 MB

  const dim3 blk(256);
  cast_bf16<<<2048, blk, 0, stream>>>(x, x_bf, 524288);
  transpose_cast<<<dim3(64, 64), blk, 0, stream>>>(Wq, w_t, 2048, 2048, 0);
  transpose_cast<<<dim3(64, 64), blk, 0, stream>>>(Wk, w_t, 2048, 2048, 2048);
  transpose_cast<<<dim3(64, 64), blk, 0, stream>>>(Wv, w_t, 2048, 2048, 4096);
  gemm_bf16_bt<short><<<dim3(48, 16), blk, 0, stream>>>(x_bf, w_t, qkv, 2048, 6144, 2048);
  gemm_f32<<<dim3(1, 32), blk, 0, stream>>>(x, Wg, g, 2048, 48, 2048);
  sigmoid_k<<<384, blk, 0, stream>>>(g, 98304);
  rope_inplace<<<8192, blk, 0, stream>>>(qkv);          // q slice
  rope_inplace<<<8192, blk, 0, stream>>>(qkv + KOFS);   // k slice
  block_mean<<<256, blk, 0, stream>>>(qkv + KOFS, kc);
  block_mean_vt<<<256, blk, 0, stream>>>(qkv + VOFS, vct);
  v_transpose<<<dim3(16, 16, 2), blk, 0, stream>>>(qkv, vt);
  cmp_sel<<<128, blk, 0, stream>>>(qkv, kc, pcb, sel);
  transpose_cast<<<dim3(64, 64), blk, 0, stream>>>(Wo, w_t, 2048, 2048, 0);
  attn_mfma<<<dim3(64, 16, 2), dim3(64), 0, stream>>>(qkv, vt, vct, pcb, sel, g, o_bf);
  gemm_bf16_bt<float><<<dim3(16, 16), blk, 0, stream>>>(o_bf, w_t, out, 2048, 2048, 2048);
}

// Round 4
// 354.800 us; speedup vs baseline: 5.0534x; 1.7244x over previous
//
#include <hip/hip_runtime.h>
#include <hip/hip_bf16.h>

// NSA forward: B=2, N=1024, D=2048, H=16, HD=128, BS=64, SEL=8, WIN=64
#define HN   16
#define HDIM 128
#define NSEQ 1024
#define NBLK 16
#define BSZ  64
#define SCALE 0.08838834764831845f
#define QKV_STR 6144   // row stride of fused qkv buffer (bf16)
#define KOFS 2048
#define VOFS 4096

typedef __attribute__((ext_vector_type(8))) short bfrag;   // 8 bf16 (4 VGPRs)
typedef __attribute__((ext_vector_type(4))) float facc;    // MFMA accumulator

__device__ __forceinline__ float bf2f(short s) {
  union { unsigned u; float f; } cv;
  cv.u = ((unsigned)(unsigned short)s) << 16;
  return cv.f;
}
__device__ __forceinline__ short f2bf(float f) {
  unsigned u = __float_as_uint(f);
  u = (u + 0x7fff + ((u >> 16) & 1)) >> 16;  // RNE
  return (short)u;
}

#define ASYNC16(gp, lp)                                                    \
  __builtin_amdgcn_global_load_lds(                                        \
      (const __attribute__((address_space(1))) void*)(gp),                 \
      (__attribute__((address_space(3))) void*)(lp), 16, 0, 0)

#define MFMA16(a, b, c) __builtin_amdgcn_mfma_f32_16x16x32_bf16(a, b, c, 0, 0, 0)

// ------------------------------------------------------------------
// fp32 -> bf16 cast, 8 elems/thread
// ------------------------------------------------------------------
__global__ __launch_bounds__(256) void cast_bf16(const float* __restrict__ src,
                                                 short* __restrict__ dst, int n8) {
  int i = blockIdx.x * 256 + threadIdx.x;
  if (i < n8) {
    const float4 a = ((const float4*)src)[2 * i];
    const float4 b = ((const float4*)src)[2 * i + 1];
    bfrag o;
    o[0] = f2bf(a.x); o[1] = f2bf(a.y); o[2] = f2bf(a.z); o[3] = f2bf(a.w);
    o[4] = f2bf(b.x); o[5] = f2bf(b.y); o[6] = f2bf(b.z); o[7] = f2bf(b.w);
    ((bfrag*)dst)[i] = o;
  }
}

// ------------------------------------------------------------------
// fp32 [rows][cols] -> bf16 transpose [cols][rows], dst row offset dofs
// ------------------------------------------------------------------
__global__ __launch_bounds__(256) void transpose_cast(const float* __restrict__ src,
                                                      short* __restrict__ dst,
                                                      int rows, int cols, int dofs) {
  __shared__ float tile[32][33];
  const int bx = blockIdx.x * 32;  // src col
  const int by = blockIdx.y * 32;  // src row
  const int tx = threadIdx.x & 31, ty = threadIdx.x >> 5;
#pragma unroll
  for (int i = 0; i < 4; ++i)
    tile[ty + 8 * i][tx] = src[(size_t)(by + ty + 8 * i) * cols + bx + tx];
  __syncthreads();
#pragma unroll
  for (int i = 0; i < 4; ++i)
    dst[(size_t)(dofs + bx + ty + 8 * i) * rows + by + tx] = f2bf(tile[tx][ty + 8 * i]);
}

// ------------------------------------------------------------------
// Wg [2048][48] fp32 -> wgt [128][2048] bf16, rows >= 48 zero-filled
// ------------------------------------------------------------------
__global__ __launch_bounds__(256) void transpose_pad_wg(const float* __restrict__ src,
                                                        short* __restrict__ dst) {
  __shared__ float tile[32][33];
  const int bx = blockIdx.x * 32;  // src col / dst row
  const int by = blockIdx.y * 32;  // src row
  const int tx = threadIdx.x & 31, ty = threadIdx.x >> 5;
#pragma unroll
  for (int i = 0; i < 4; ++i) {
    const int c = bx + tx;
    tile[ty + 8 * i][tx] = (c < 48) ? src[(size_t)(by + ty + 8 * i) * 48 + c] : 0.f;
  }
  __syncthreads();
#pragma unroll
  for (int i = 0; i < 4; ++i)
    dst[(size_t)(bx + ty + 8 * i) * 2048 + by + tx] = f2bf(tile[tx][ty + 8 * i]);
}

// ------------------------------------------------------------------
// bf16 MFMA GEMM, m97 structure: C[M][N] = A[M][K] * Bt[N][K]^T
// ------------------------------------------------------------------
__device__ __forceinline__ void store_c(float* p, float v) { *p = v; }
__device__ __forceinline__ void store_c(short* p, float v) { *p = f2bf(v); }

template <typename OT>
__global__ __launch_bounds__(256) void gemm_bf16_bt(const short* __restrict__ A,
                                                    const short* __restrict__ Bt,
                                                    OT* __restrict__ C,
                                                    int M, int N, int K) {
  __shared__ short As[128 * 32];
  __shared__ short Bs[128 * 32];
  const int t = threadIdx.x;
  const int l = t & 63, w = t >> 6;
  const int wr = w >> 1, wc = w & 1;
  const int row0 = blockIdx.y * 128, col0 = blockIdx.x * 128;
  facc acc[4][4] = {};

  const int sr = t >> 2;
  const int sk = (t & 3) * 8;
  const short* Ag0 = A + (size_t)(row0 + sr) * K + sk;
  const short* Ag1 = Ag0 + (size_t)64 * K;
  const short* Bg0 = Bt + (size_t)(col0 + sr) * K + sk;
  const short* Bg1 = Bg0 + (size_t)64 * K;
  short* la = As + t * 8;
  short* lb = Bs + t * 8;

  const int lm = l & 15;
  const int lk = (l >> 4) * 8;

  for (int k0 = 0; k0 < K; k0 += 32) {
    ASYNC16(Ag0 + k0, la);
    ASYNC16(Ag1 + k0, la + 2048);
    ASYNC16(Bg0 + k0, lb);
    ASYNC16(Bg1 + k0, lb + 2048);
    __syncthreads();
    bfrag af[4], bf[4];
#pragma unroll
    for (int i = 0; i < 4; ++i)
      af[i] = *(const bfrag*)&As[(wr * 64 + i * 16 + lm) * 32 + lk];
#pragma unroll
    for (int j = 0; j < 4; ++j)
      bf[j] = *(const bfrag*)&Bs[(wc * 64 + j * 16 + lm) * 32 + lk];
#pragma unroll
    for (int i = 0; i < 4; ++i)
#pragma unroll
      for (int j = 0; j < 4; ++j)
        acc[i][j] = MFMA16(af[i], bf[j], acc[i][j]);
    __syncthreads();
  }

  const int orow = row0 + wr * 64 + (l >> 4) * 4;
  const int ocol = col0 + wc * 64 + lm;
#pragma unroll
  for (int i = 0; i < 4; ++i)
#pragma unroll
    for (int j = 0; j < 4; ++j)
#pragma unroll
      for (int rr = 0; rr < 4; ++rr)
        store_c(&C[(size_t)(orow + i * 16 + rr) * N + ocol + j * 16], acc[i][j][rr]);
}

__global__ __launch_bounds__(256) void sigmoid_k(float* __restrict__ p, int n) {
  int i = blockIdx.x * 256 + threadIdx.x;
  if (i < n) p[i] = 1.0f / (1.0f + __expf(-p[i]));
}

// ------------------------------------------------------------------
// RoPE in place on bf16 qkv slice, row stride QKV_STR
// ------------------------------------------------------------------
__global__ __launch_bounds__(256) void rope_inplace(short* __restrict__ p) {
  int i = blockIdx.x * 256 + threadIdx.x;  // 2097152
  int d = i & 63;
  int h = (i >> 6) & 15;
  int n = (i >> 10) & 1023;
  int b = i >> 20;
  short* base = p + (size_t)(b * NSEQ + n) * QKV_STR + h * HDIM + d;
  float inv = expf(-(float)d * (9.210340371976184f / 64.0f));
  float th = (float)n * inv;
  float sn, cs;
  sincosf(th, &sn, &cs);
  float t1 = bf2f(base[0]), t2 = bf2f(base[64]);
  base[0]  = f2bf(t1 * cs - t2 * sn);
  base[64] = f2bf(t1 * sn + t2 * cs);
}

// ------------------------------------------------------------------
// Block mean (roped K) -> f32 kc [b][m][h][d]
// ------------------------------------------------------------------
__global__ __launch_bounds__(256) void block_mean(const short* __restrict__ src,
                                                  float* __restrict__ dst) {
  int i = blockIdx.x * 256 + threadIdx.x;  // 65536
  int d = i & 127;
  int h = (i >> 7) & 15;
  int m = (i >> 11) & 15;
  int b = i >> 15;
  const short* p = src + (size_t)(b * NSEQ + m * BSZ) * QKV_STR + h * HDIM + d;
  float acc = 0.f;
#pragma unroll 8
  for (int j = 0; j < 64; ++j) acc += bf2f(p[(size_t)j * QKV_STR]);
  dst[i] = acc * (1.0f / 64.0f);
}

// ------------------------------------------------------------------
// Block mean (V) -> bf16 vcT [b][h][d][m]  (B-operand layout for cmp MFMA)
// ------------------------------------------------------------------
__global__ __launch_bounds__(256) void block_mean_vt(const short* __restrict__ src,
                                                     short* __restrict__ vct) {
  int i = blockIdx.x * 256 + threadIdx.x;  // 65536
  int d = i & 127;
  int h = (i >> 7) & 15;
  int m = (i >> 11) & 15;
  int b = i >> 15;
  const short* p = src + (size_t)(b * NSEQ + m * BSZ) * QKV_STR + h * HDIM + d;
  float acc = 0.f;
#pragma unroll 8
  for (int j = 0; j < 64; ++j) acc += bf2f(p[(size_t)j * QKV_STR]);
  vct[(((size_t)(b * HN + h) * 128) + d) * 16 + m] = f2bf(acc * (1.0f / 64.0f));
}

// ------------------------------------------------------------------
// V transpose: qkv V slice -> vt[b][h][d][n] bf16
// ------------------------------------------------------------------
__global__ __launch_bounds__(256) void v_transpose(const short* __restrict__ qkv,
                                                   short* __restrict__ vt) {
  __shared__ short tile[64][136];
  const int n0 = blockIdx.x * 64;
  const int h = blockIdx.y, b = blockIdx.z;
  const int t = threadIdx.x;
#pragma unroll
  for (int it = 0; it < 4; ++it) {
    int idx = t + 256 * it;           // 0..1023
    int row = idx >> 4, ch = idx & 15;
    *(bfrag*)&tile[row][ch * 8] =
        *(const bfrag*)&qkv[(size_t)(b * NSEQ + n0 + row) * QKV_STR + VOFS + h * HDIM + ch * 8];
  }
  __syncthreads();
#pragma unroll
  for (int it = 0; it < 4; ++it) {
    int idx = t + 256 * it;           // 0..1023
    int d = idx >> 3, ch = idx & 7;
    bfrag tv;
#pragma unroll
    for (int j = 0; j < 8; ++j) tv[j] = tile[ch * 8 + j][d];
    *(bfrag*)&vt[(((size_t)(b * HN + h) * 128) + d) * 1024 + n0 + ch * 8] = tv;
  }
}

// ------------------------------------------------------------------
// Compressed probs (bf16 pc [b][h][n][16]) + top-8 selection bitmask
// ------------------------------------------------------------------
__global__ __launch_bounds__(256) void cmp_sel(const short* __restrict__ qkv,
                                               const float* __restrict__ kc,
                                               short* __restrict__ pc,
                                               int* __restrict__ sel) {
  int i = blockIdx.x * 256 + threadIdx.x;  // B*H*N = 32768
  int n = i & 1023;
  int h = (i >> 10) & 15;
  int b = i >> 14;
  const short* qp = qkv + (size_t)(b * NSEQ + n) * QKV_STR + h * HDIM;
  float qf[HDIM];
#pragma unroll
  for (int d0 = 0; d0 < HDIM; d0 += 8) {
    bfrag qv = *(const bfrag*)&qp[d0];
#pragma unroll
    for (int dd = 0; dd < 8; ++dd) qf[d0 + dd] = bf2f(qv[dd]);
  }
  const int nv = (n + 1) >> 6;
  float s[NBLK];
  float mx = -1e30f;
  for (int m = 0; m < nv; ++m) {
    const float* kp = kc + ((size_t)((b * NBLK + m) * HN + h) << 7);
    float dot = 0.f;
    for (int d = 0; d < HDIM; d += 4) {
      const float4 kv = *(const float4*)&kp[d];
      dot += qf[d] * kv.x + qf[d + 1] * kv.y + qf[d + 2] * kv.z + qf[d + 3] * kv.w;
    }
    s[m] = dot * SCALE;
    mx = fmaxf(mx, s[m]);
  }
  float den = 0.f;
  for (int m = 0; m < nv; ++m) { s[m] = __expf(s[m] - mx); den += s[m]; }
  const float rden = (nv > 0) ? 1.0f / den : 0.f;
  float p[NBLK];
#pragma unroll
  for (int m = 0; m < NBLK; ++m) p[m] = (m < nv) ? s[m] * rden : 0.f;
  bfrag o0, o1;
#pragma unroll
  for (int m = 0; m < 8; ++m) { o0[m] = f2bf(p[m]); o1[m] = f2bf(p[m + 8]); }
  bfrag* pout = (bfrag*)(pc + (size_t)i * 16);
  pout[0] = o0; pout[1] = o1;
  p[n >> 6] += 2.0f;
  int mask = 0;
#pragma unroll
  for (int ss = 0; ss < 8; ++ss) {
    int best = 0;
    float bv = -1e30f;
#pragma unroll
    for (int m = 0; m < NBLK; ++m)
      if (p[m] > bv) { bv = p[m]; best = m; }
    mask |= 1 << best;
    p[best] = -1e30f;
  }
  sel[i] = mask;
}

// ------------------------------------------------------------------
// MFMA attention: one wave per (b, h, 16-row tile).
// XCD-swizzled 1-D grid: each XCD owns 4 whole (b,h) pairs so its
// K/V slices (2 MB) stay L2-resident. Batched global loads with
// ping-pong prefetch to break the load->MFMA serial chain.
// ------------------------------------------------------------------
__global__ __launch_bounds__(64, 2) void attn_mfma(
    const short* __restrict__ qkv, const short* __restrict__ vt,
    const short* __restrict__ vct, const short* __restrict__ pc,
    const int* __restrict__ sel, const float* __restrict__ g,
    short* __restrict__ o) {
  // swizzle: fid -> (xcd, idx); xcd owns pairs [4*xcd, 4*xcd+4)
  const int fid = blockIdx.x;
  const int xcd = fid & 7;
  const int idx = fid >> 3;            // 0..255
  const int pair = (xcd << 2) | (idx >> 6);
  const int rt = idx & 63;
  const int h = pair & 15, b = pair >> 4;

  const int l = threadIdx.x;
  const int lm = l & 15, hi = l >> 4;
  const int nbase = rt * 16;

  __shared__ short p_slc[1024];
  __shared__ short p_swa[1024];

  // Q A-fragments (row = lm, k = 32*ks + 8*hi + j)
  const short* qrow = qkv + (size_t)(b * NSEQ + nbase + lm) * QKV_STR + h * HDIM;
  bfrag qf[4];
#pragma unroll
  for (int ks = 0; ks < 4; ++ks) qf[ks] = *(const bfrag*)&qrow[32 * ks + 8 * hi];

  // selection bits
  int selrow = sel[(size_t)(b * HN + h) * NSEQ + nbase + lm];
  int uni = selrow;
#pragma unroll
  for (int m = 1; m < 16; m <<= 1) uni |= __shfl_xor(uni, m);
  int sel4[4];
#pragma unroll
  for (int rg = 0; rg < 4; ++rg) sel4[rg] = __shfl(selrow, 4 * hi + rg);

  const int thi = nbase >> 6;                      // last causal tile
  const int tlo = (nbase >= 64) ? ((nbase - 64) >> 6) : 0;
  const int wmask = (int)((2u << thi) - (1u << tlo));

  facc acc_slc[8] = {}, acc_swa[8] = {}, acc_cmp[8] = {};
  float ps_s[4] = {0.f, 0.f, 0.f, 0.f}, ps_w[4] = {0.f, 0.f, 0.f, 0.f};

  // ---- compressed branch: O_cmp = Pc[16x16] * Vc[16x128], K padded to 32
  {
    bfrag pa = {};
    if (hi < 2)
      pa = *(const bfrag*)&pc[((size_t)(b * HN + h) * NSEQ + nbase + lm) * 16 + 8 * hi];
    bfrag vb[8];
#pragma unroll
    for (int df = 0; df < 8; ++df) {
      bfrag z = {};
      vb[df] = (hi < 2)
          ? *(const bfrag*)&vct[(((size_t)(b * HN + h) * 128) + 16 * df + lm) * 16 + 8 * hi]
          : z;
    }
#pragma unroll
    for (int df = 0; df < 8; ++df) acc_cmp[df] = MFMA16(pa, vb[df], acc_cmp[df]);
  }

  // ---- main tile loop
  const short* kbase0 = qkv + (size_t)(b * NSEQ) * QKV_STR + KOFS + h * HDIM + 8 * hi;
  const short* vtb0 = vt + ((size_t)(b * HN + h) * 128) * 1024 + 8 * hi;

  for (int ct = 0; ct <= thi; ++ct) {
    const bool do_s = (uni >> ct) & 1;
    const bool do_w = (wmask >> ct) & 1;
    if (!do_s && !do_w) continue;

    // ---- QK^T: batched K loads, ping-pong prefetch across f
    facc sacc[4] = {};
    {
      const short* kr = kbase0 + (size_t)(ct * 64 + lm) * QKV_STR;
      bfrag ka0 = *(const bfrag*)(kr);
      bfrag ka1 = *(const bfrag*)(kr + 32);
      bfrag ka2 = *(const bfrag*)(kr + 64);
      bfrag ka3 = *(const bfrag*)(kr + 96);
#pragma unroll
      for (int f = 0; f < 4; ++f) {
        bfrag kn0 = ka0, kn1 = ka1, kn2 = ka2, kn3 = ka3;
        if (f < 3) {
          const short* krn = kbase0 + (size_t)(ct * 64 + 16 * (f + 1) + lm) * QKV_STR;
          kn0 = *(const bfrag*)(krn);
          kn1 = *(const bfrag*)(krn + 32);
          kn2 = *(const bfrag*)(krn + 64);
          kn3 = *(const bfrag*)(krn + 96);
        }
        sacc[f] = MFMA16(qf[0], ka0, sacc[f]);
        sacc[f] = MFMA16(qf[1], ka1, sacc[f]);
        sacc[f] = MFMA16(qf[2], ka2, sacc[f]);
        sacc[f] = MFMA16(qf[3], ka3, sacc[f]);
        ka0 = kn0; ka1 = kn1; ka2 = kn2; ka3 = kn3;
      }
    }

    // exp + masks + partial sums + LDS P write (XOR-swizzled)
#pragma unroll
    for (int f = 0; f < 4; ++f) {
      const int col = ct * 64 + 16 * f + lm;
#pragma unroll
      for (int rg = 0; rg < 4; ++rg) {
        const int row = nbase + 4 * hi + rg;
        float e = __expf(sacc[f][rg] * SCALE);
        e = (col <= row) ? e : 0.f;
        float es = ((sel4[rg] >> ct) & 1) ? e : 0.f;
        float ew = (row - col <= 64) ? e : 0.f;
        ps_s[rg] += es;
        ps_w[rg] += ew;
        const int srow = 4 * hi + rg;
        const int sidx = (64 * srow + 16 * f + lm) ^ ((srow & 7) << 3);
        if (do_s) p_slc[sidx] = f2bf(es);
        if (do_w) p_swa[sidx] = f2bf(ew);
      }
    }
    __syncthreads();

    // ---- PV: batched V loads per k-slot, then MFMA cluster
    const short* vtb = vtb0 + ct * 64;
#pragma unroll
    for (int ks = 0; ks < 2; ++ks) {
      const int ridx = (64 * lm + 8 * hi + 32 * ks) ^ ((lm & 7) << 3);
      bfrag pas = {}, paw = {};
      if (do_s) pas = *(const bfrag*)&p_slc[ridx];
      if (do_w) paw = *(const bfrag*)&p_swa[ridx];
      bfrag vb[8];
#pragma unroll
      for (int df = 0; df < 8; ++df)
        vb[df] = *(const bfrag*)&vtb[(size_t)(16 * df + lm) * 1024 + 32 * ks];
#pragma unroll
      for (int df = 0; df < 8; ++df) {
        if (do_s) acc_slc[df] = MFMA16(pas, vb[df], acc_slc[df]);
        if (do_w) acc_swa[df] = MFMA16(paw, vb[df], acc_swa[df]);
      }
    }
    __syncthreads();
  }

  // ---- denominators: reduce across the 16 col-lanes
#pragma unroll
  for (int m = 1; m < 16; m <<= 1) {
#pragma unroll
    for (int rg = 0; rg < 4; ++rg) {
      ps_s[rg] += __shfl_xor(ps_s[rg], m);
      ps_w[rg] += __shfl_xor(ps_w[rg], m);
    }
  }

  float inv_s[4], inv_w[4], gcv[4], gsv[4], gwv[4];
#pragma unroll
  for (int rg = 0; rg < 4; ++rg) {
    inv_s[rg] = 1.0f / ps_s[rg];
    inv_w[rg] = 1.0f / ps_w[rg];
    const size_t grow = (size_t)(b * NSEQ + nbase + 4 * hi + rg) * 128;
    gcv[rg] = g[grow + h];
    gsv[rg] = g[grow + 16 + h];
    gwv[rg] = g[grow + 32 + h];
  }

  short* obase = o + (size_t)(b * NSEQ + nbase) * 2048 + h * HDIM;
#pragma unroll
  for (int df = 0; df < 8; ++df)
#pragma unroll
    for (int rg = 0; rg < 4; ++rg) {
      float val = gcv[rg] * acc_cmp[df][rg] +
                  gsv[rg] * acc_slc[df][rg] * inv_s[rg] +
                  gwv[rg] * acc_swa[df][rg] * inv_w[rg];
      obase[(size_t)(4 * hi + rg) * 2048 + 16 * df + lm] = f2bf(val);
    }
}

// ------------------------------------------------------------------
extern "C" void kernel_launch(void* const* d_in, const int* in_sizes, int n_in,
                              void* d_out, int out_size, void* d_ws, size_t ws_size,
                              hipStream_t stream) {
  const float* x  = (const float*)d_in[0];
  const float* Wq = (const float*)d_in[1];
  const float* Wk = (const float*)d_in[2];
  const float* Wv = (const float*)d_in[3];
  const float* Wg = (const float*)d_in[4];
  const float* Wo = (const float*)d_in[5];
  float* out = (float*)d_out;

  char* w = (char*)d_ws;
  short* x_bf = (short*)w;            // 8.4 MB (reused as o_bf after gate gemm)
  short* o_bf = x_bf;
  w += (size_t)2048 * 2048 * 2;
  short* w_t  = (short*)w;            // 25.2 MB (reused for Wo^T)
  w += (size_t)6144 * 2048 * 2;
  short* qkv  = (short*)w;            // 25.2 MB
  w += (size_t)2048 * 6144 * 2;
  float* gf   = (float*)w; w += (size_t)262144 * 4;   // g, stride 128
  float* kc   = (float*)w; w += (size_t)65536 * 4;
  short* vct  = (short*)w; w += (size_t)65536 * 2;
  short* pcb  = (short*)w; w += (size_t)524288 * 2;
  int*   sel  = (int*)w;   w += (size_t)32768 * 4;
  short* vt   = (short*)w; w += (size_t)4194304 * 2;  // 8.4 MB
  short* wgt  = (short*)w; w += (size_t)128 * 2048 * 2;

  const dim3 blk(256);
  cast_bf16<<<2048, blk, 0, stream>>>(x, x_bf, 524288);
  transpose_cast<<<dim3(64, 64), blk, 0, stream>>>(Wq, w_t, 2048, 2048, 0);
  transpose_cast<<<dim3(64, 64), blk, 0, stream>>>(Wk, w_t, 2048, 2048, 2048);
  transpose_cast<<<dim3(64, 64), blk, 0, stream>>>(Wv, w_t, 2048, 2048, 4096);
  gemm_bf16_bt<short><<<dim3(48, 16), blk, 0, stream>>>(x_bf, w_t, qkv, 2048, 6144, 2048);
  transpose_pad_wg<<<dim3(4, 64), blk, 0, stream>>>(Wg, wgt);
  gemm_bf16_bt<float><<<dim3(1, 16), blk, 0, stream>>>(x_bf, wgt, gf, 2048, 128, 2048);
  sigmoid_k<<<1024, blk, 0, stream>>>(gf, 262144);
  rope_inplace<<<8192, blk, 0, stream>>>(qkv);          // q slice
  rope_inplace<<<8192, blk, 0, stream>>>(qkv + KOFS);   // k slice
  block_mean<<<256, blk, 0, stream>>>(qkv + KOFS, kc);
  block_mean_vt<<<256, blk, 0, stream>>>(qkv + VOFS, vct);
  v_transpose<<<dim3(16, 16, 2), blk, 0, stream>>>(qkv, vt);
  cmp_sel<<<128, blk, 0, stream>>>(qkv, kc, pcb, sel);
  transpose_cast<<<dim3(64, 64), blk, 0, stream>>>(Wo, w_t, 2048, 2048, 0);
  attn_mfma<<<2048, dim3(64), 0, stream>>>(qkv, vt, vct, pcb, sel, gf, o_bf);
  gemm_bf16_bt<float><<<dim3(16, 16), blk, 0, stream>>>(o_bf, w_t, out, 2048, 2048, 2048);
}

// Round 5
// 303.244 us; speedup vs baseline: 5.9126x; 1.1700x over previous
//
#include <hip/hip_runtime.h>
#include <hip/hip_bf16.h>

// NSA forward: B=2, N=1024, D=2048, H=16, HD=128, BS=64, SEL=8, WIN=64
#define HN   16
#define HDIM 128
#define NSEQ 1024
#define NBLK 16
#define BSZ  64
#define SCALE 0.08838834764831845f
#define QKV_STR 6272   // row stride of fused qkv+gate buffer (bf16)
#define KOFS 2048
#define VOFS 4096
#define GOFS 6144

typedef __attribute__((ext_vector_type(8))) short bfrag;   // 8 bf16 (4 VGPRs)
typedef __attribute__((ext_vector_type(4))) float facc;    // MFMA accumulator

__device__ __forceinline__ float bf2f(short s) {
  union { unsigned u; float f; } cv;
  cv.u = ((unsigned)(unsigned short)s) << 16;
  return cv.f;
}
__device__ __forceinline__ short f2bf(float f) {
  unsigned u = __float_as_uint(f);
  u = (u + 0x7fff + ((u >> 16) & 1)) >> 16;  // RNE
  return (short)u;
}

#define ASYNC16(gp, lp)                                                    \
  __builtin_amdgcn_global_load_lds(                                        \
      (const __attribute__((address_space(1))) void*)(gp),                 \
      (__attribute__((address_space(3))) void*)(lp), 16, 0, 0)

#define MFMA16(a, b, c) __builtin_amdgcn_mfma_f32_16x16x32_bf16(a, b, c, 0, 0, 0)

// ------------------------------------------------------------------
// prep: z=0..2 -> Wq/Wk/Wv transpose-cast into w_t rows z*2048..
//       z=3   -> Wg [2048][48] transposed + zero-padded to rows 6144..6271
//       z=4   -> x cast to bf16 (no transpose)
// ------------------------------------------------------------------
__global__ __launch_bounds__(256) void prep(const float* __restrict__ Wq,
                                            const float* __restrict__ Wk,
                                            const float* __restrict__ Wv,
                                            const float* __restrict__ Wg,
                                            const float* __restrict__ x,
                                            short* __restrict__ w_t,
                                            short* __restrict__ x_bf) {
  __shared__ float tile[32][33];
  const int z = blockIdx.z;
  const int bx = blockIdx.x * 32, by = blockIdx.y * 32;
  const int tx = threadIdx.x & 31, ty = threadIdx.x >> 5;
  if (z == 4) {
#pragma unroll
    for (int i = 0; i < 4; ++i) {
      const int row = by + ty + 8 * i;
      x_bf[(size_t)row * 2048 + bx + tx] = f2bf(x[(size_t)row * 2048 + bx + tx]);
    }
    return;
  }
  if (z == 3) {
    if (blockIdx.x >= 4) return;  // only 128 dst rows
#pragma unroll
    for (int i = 0; i < 4; ++i) {
      const int c = bx + tx;
      tile[ty + 8 * i][tx] = (c < 48) ? Wg[(size_t)(by + ty + 8 * i) * 48 + c] : 0.f;
    }
    __syncthreads();
#pragma unroll
    for (int i = 0; i < 4; ++i)
      w_t[(size_t)(GOFS + bx + ty + 8 * i) * 2048 + by + tx] = f2bf(tile[tx][ty + 8 * i]);
    return;
  }
  const float* src = (z == 0) ? Wq : (z == 1) ? Wk : Wv;
#pragma unroll
  for (int i = 0; i < 4; ++i)
    tile[ty + 8 * i][tx] = src[(size_t)(by + ty + 8 * i) * 2048 + bx + tx];
  __syncthreads();
#pragma unroll
  for (int i = 0; i < 4; ++i)
    w_t[(size_t)(z * 2048 + bx + ty + 8 * i) * 2048 + by + tx] = f2bf(tile[tx][ty + 8 * i]);
}

// ------------------------------------------------------------------
// Wo transpose (reuses w_t after qkv gemm)
// ------------------------------------------------------------------
__global__ __launch_bounds__(256) void transpose_cast(const float* __restrict__ src,
                                                      short* __restrict__ dst) {
  __shared__ float tile[32][33];
  const int bx = blockIdx.x * 32, by = blockIdx.y * 32;
  const int tx = threadIdx.x & 31, ty = threadIdx.x >> 5;
#pragma unroll
  for (int i = 0; i < 4; ++i)
    tile[ty + 8 * i][tx] = src[(size_t)(by + ty + 8 * i) * 2048 + bx + tx];
  __syncthreads();
#pragma unroll
  for (int i = 0; i < 4; ++i)
    dst[(size_t)(bx + ty + 8 * i) * 2048 + by + tx] = f2bf(tile[tx][ty + 8 * i]);
}

// ------------------------------------------------------------------
// bf16 MFMA GEMM (m97): C[M][N] = A[M][K] * Bt[N][K]^T, 1-D grid,
// XCD column-chunk swizzle (requires gridDim.x % 8 == 0).
// ------------------------------------------------------------------
__device__ __forceinline__ void store_c(float* p, float v) { *p = v; }
__device__ __forceinline__ void store_c(short* p, float v) { *p = f2bf(v); }

template <typename OT>
__global__ __launch_bounds__(256) void gemm_bf16_bt(const short* __restrict__ A,
                                                    const short* __restrict__ Bt,
                                                    OT* __restrict__ C,
                                                    int M, int N, int K) {
  __shared__ short As[128 * 32];
  __shared__ short Bs[128 * 32];
  const int t = threadIdx.x;
  const int l = t & 63, w = t >> 6;
  const int wr = w >> 1, wc = w & 1;
  const int nwg = gridDim.x;
  const int L = blockIdx.x;
  const int wg = (L & 7) * (nwg >> 3) + (L >> 3);
  const int nrow = M >> 7;
  const int row0 = (wg % nrow) * 128, col0 = (wg / nrow) * 128;
  facc acc[4][4] = {};

  const int sr = t >> 2;
  const int sk = (t & 3) * 8;
  const short* Ag0 = A + (size_t)(row0 + sr) * K + sk;
  const short* Ag1 = Ag0 + (size_t)64 * K;
  const short* Bg0 = Bt + (size_t)(col0 + sr) * K + sk;
  const short* Bg1 = Bg0 + (size_t)64 * K;
  short* la = As + t * 8;
  short* lb = Bs + t * 8;

  const int lm = l & 15;
  const int lk = (l >> 4) * 8;

  for (int k0 = 0; k0 < K; k0 += 32) {
    ASYNC16(Ag0 + k0, la);
    ASYNC16(Ag1 + k0, la + 2048);
    ASYNC16(Bg0 + k0, lb);
    ASYNC16(Bg1 + k0, lb + 2048);
    __syncthreads();
    bfrag af[4], bf[4];
#pragma unroll
    for (int i = 0; i < 4; ++i)
      af[i] = *(const bfrag*)&As[(wr * 64 + i * 16 + lm) * 32 + lk];
#pragma unroll
    for (int j = 0; j < 4; ++j)
      bf[j] = *(const bfrag*)&Bs[(wc * 64 + j * 16 + lm) * 32 + lk];
#pragma unroll
    for (int i = 0; i < 4; ++i)
#pragma unroll
      for (int j = 0; j < 4; ++j)
        acc[i][j] = MFMA16(af[i], bf[j], acc[i][j]);
    __syncthreads();
  }

  const int orow = row0 + wr * 64 + (l >> 4) * 4;
  const int ocol = col0 + wc * 64 + lm;
#pragma unroll
  for (int i = 0; i < 4; ++i)
#pragma unroll
    for (int j = 0; j < 4; ++j)
#pragma unroll
      for (int rr = 0; rr < 4; ++rr)
        store_c(&C[(size_t)(orow + i * 16 + rr) * N + ocol + j * 16], acc[i][j][rr]);
}

// ------------------------------------------------------------------
// RoPE cos/sin table [n][d] (d<64), float2
// ------------------------------------------------------------------
__global__ __launch_bounds__(256) void rope_tbl(float2* __restrict__ tbl) {
  int i = blockIdx.x * 256 + threadIdx.x;  // 65536
  int d = i & 63, n = i >> 6;
  float inv = expf(-(float)d * (9.210340371976184f / 64.0f));
  float sn, cs;
  sincosf((float)n * inv, &sn, &cs);
  tbl[i] = make_float2(cs, sn);
}

// ------------------------------------------------------------------
// RoPE in place on q AND k slices, table-based, 8 dims/thread
// ------------------------------------------------------------------
__global__ __launch_bounds__(256) void rope_qk(short* __restrict__ qkv,
                                               const float2* __restrict__ tbl) {
  int i = blockIdx.x * 256 + threadIdx.x;  // 524288
  int c = i & 7;
  int h = (i >> 3) & 15;
  int qk = (i >> 7) & 1;
  int n = (i >> 8) & 1023;
  int b = i >> 18;
  short* base = qkv + (size_t)(b * NSEQ + n) * QKV_STR + qk * KOFS + h * HDIM + c * 8;
  const float2* tp = tbl + n * 64 + c * 8;
  bfrag t1 = *(const bfrag*)base, t2 = *(const bfrag*)(base + 64);
  bfrag o1, o2;
#pragma unroll
  for (int j = 0; j < 8; ++j) {
    float2 cssn = tp[j];
    float a = bf2f(t1[j]), bb = bf2f(t2[j]);
    o1[j] = f2bf(a * cssn.x - bb * cssn.y);
    o2[j] = f2bf(a * cssn.y + bb * cssn.x);
  }
  *(bfrag*)base = o1;
  *(bfrag*)(base + 64) = o2;
}

// ------------------------------------------------------------------
// Block mean (roped K) -> f32 kc [b][m][h][d]
// ------------------------------------------------------------------
__global__ __launch_bounds__(256) void block_mean(const short* __restrict__ src,
                                                  float* __restrict__ dst) {
  int i = blockIdx.x * 256 + threadIdx.x;  // 65536
  int d = i & 127;
  int h = (i >> 7) & 15;
  int m = (i >> 11) & 15;
  int b = i >> 15;
  const short* p = src + (size_t)(b * NSEQ + m * BSZ) * QKV_STR + h * HDIM + d;
  float acc = 0.f;
#pragma unroll 8
  for (int j = 0; j < 64; ++j) acc += bf2f(p[(size_t)j * QKV_STR]);
  dst[i] = acc * (1.0f / 64.0f);
}

// ------------------------------------------------------------------
// V transpose -> vt[b][h][d][n], fused V block-mean -> vct[b][h][d][m]
// ------------------------------------------------------------------
__global__ __launch_bounds__(256) void v_transpose(const short* __restrict__ qkv,
                                                   short* __restrict__ vt,
                                                   short* __restrict__ vct) {
  __shared__ short tile[64][136];
  const int n0 = blockIdx.x * 64;
  const int h = blockIdx.y, b = blockIdx.z;
  const int t = threadIdx.x;
#pragma unroll
  for (int it = 0; it < 4; ++it) {
    int idx = t + 256 * it;
    int row = idx >> 4, ch = idx & 15;
    *(bfrag*)&tile[row][ch * 8] =
        *(const bfrag*)&qkv[(size_t)(b * NSEQ + n0 + row) * QKV_STR + VOFS + h * HDIM + ch * 8];
  }
  __syncthreads();
#pragma unroll
  for (int it = 0; it < 4; ++it) {
    int idx = t + 256 * it;
    int d = idx >> 3, ch = idx & 7;
    bfrag tv;
    float s = 0.f;
#pragma unroll
    for (int j = 0; j < 8; ++j) {
      tv[j] = tile[ch * 8 + j][d];
      s += bf2f(tv[j]);
    }
    *(bfrag*)&vt[(((size_t)(b * HN + h) * 128) + d) * 1024 + n0 + ch * 8] = tv;
    s += __shfl_down(s, 4);
    s += __shfl_down(s, 2);
    s += __shfl_down(s, 1);
    if ((t & 7) == 0)
      vct[(((size_t)(b * HN + h) * 128) + d) * 16 + (n0 >> 6)] = f2bf(s * (1.0f / 64.0f));
  }
}

// ------------------------------------------------------------------
// Compressed probs (bf16 pc [b][h][n][16]) + top-8 selection bitmask
// ------------------------------------------------------------------
__global__ __launch_bounds__(256) void cmp_sel(const short* __restrict__ qkv,
                                               const float* __restrict__ kc,
                                               short* __restrict__ pc,
                                               int* __restrict__ sel) {
  int i = blockIdx.x * 256 + threadIdx.x;  // B*H*N = 32768
  int n = i & 1023;
  int h = (i >> 10) & 15;
  int b = i >> 14;
  const short* qp = qkv + (size_t)(b * NSEQ + n) * QKV_STR + h * HDIM;
  float qf[HDIM];
#pragma unroll
  for (int d0 = 0; d0 < HDIM; d0 += 8) {
    bfrag qv = *(const bfrag*)&qp[d0];
#pragma unroll
    for (int dd = 0; dd < 8; ++dd) qf[d0 + dd] = bf2f(qv[dd]);
  }
  const int nv = (n + 1) >> 6;
  float s[NBLK];
  float mx = -1e30f;
  for (int m = 0; m < nv; ++m) {
    const float* kp = kc + ((size_t)((b * NBLK + m) * HN + h) << 7);
    float dot = 0.f;
    for (int d = 0; d < HDIM; d += 4) {
      const float4 kv = *(const float4*)&kp[d];
      dot += qf[d] * kv.x + qf[d + 1] * kv.y + qf[d + 2] * kv.z + qf[d + 3] * kv.w;
    }
    s[m] = dot * SCALE;
    mx = fmaxf(mx, s[m]);
  }
  float den = 0.f;
  for (int m = 0; m < nv; ++m) { s[m] = __expf(s[m] - mx); den += s[m]; }
  const float rden = (nv > 0) ? 1.0f / den : 0.f;
  float p[NBLK];
#pragma unroll
  for (int m = 0; m < NBLK; ++m) p[m] = (m < nv) ? s[m] * rden : 0.f;
  bfrag o0, o1;
#pragma unroll
  for (int m = 0; m < 8; ++m) { o0[m] = f2bf(p[m]); o1[m] = f2bf(p[m + 8]); }
  bfrag* pout = (bfrag*)(pc + (size_t)i * 16);
  pout[0] = o0; pout[1] = o1;
  p[n >> 6] += 2.0f;
  int mask = 0;
#pragma unroll
  for (int ss = 0; ss < 8; ++ss) {
    int best = 0;
    float bv = -1e30f;
#pragma unroll
    for (int m = 0; m < NBLK; ++m)
      if (p[m] > bv) { bv = p[m]; best = m; }
    mask |= 1 << best;
    p[best] = -1e30f;
  }
  sel[i] = mask;
}

// ------------------------------------------------------------------
// MFMA attention. One wave per (b,h,16-row tile). XCD-swizzled grid,
// heavy-first (large rt dispatched first). Pipelined K loads (stream
// next row-group / next tile during MFMA), V loads hoisted above the
// exp/LDS phase. cmp branch + gating in epilogue (sigmoid inline).
// ------------------------------------------------------------------
__global__ __launch_bounds__(64, 2) void attn_mfma(
    const short* __restrict__ qkv, const short* __restrict__ vt,
    const short* __restrict__ vct, const short* __restrict__ pc,
    const int* __restrict__ sel, short* __restrict__ o) {
  const int fid = blockIdx.x;
  const int xcd = fid & 7;
  const int idx = fid >> 3;              // 0..255
  const int pair = (xcd << 2) | (idx & 3);
  const int rt = 63 - (idx >> 2);        // heavy tiles first
  const int h = pair & 15, b = pair >> 4;

  const int l = threadIdx.x;
  const int lm = l & 15, hi = l >> 4;
  const int nbase = rt * 16;

  __shared__ short p_slc[1024];
  __shared__ short p_swa[1024];

  // Q A-fragments
  const short* qrow = qkv + (size_t)(b * NSEQ + nbase + lm) * QKV_STR + h * HDIM;
  bfrag qf[4];
#pragma unroll
  for (int ks = 0; ks < 4; ++ks) qf[ks] = *(const bfrag*)&qrow[32 * ks + 8 * hi];

  // selection bits
  int selrow = sel[(size_t)(b * HN + h) * NSEQ + nbase + lm];
  int uni = selrow;
#pragma unroll
  for (int m = 1; m < 16; m <<= 1) uni |= __shfl_xor(uni, m);
  int sel4[4];
#pragma unroll
  for (int rg = 0; rg < 4; ++rg) sel4[rg] = __shfl(selrow, 4 * hi + rg);

  const int thi = nbase >> 6;
  const int tlo = (nbase >= 64) ? ((nbase - 64) >> 6) : 0;
  const int wmask = (int)((2u << thi) - (1u << tlo));
  const unsigned am = (unsigned)(uni | wmask) & (unsigned)((2u << thi) - 1);

  facc acc_slc[8] = {}, acc_swa[8] = {};
  float ps_s[4] = {0.f, 0.f, 0.f, 0.f}, ps_w[4] = {0.f, 0.f, 0.f, 0.f};

  const short* kbase0 = qkv + (size_t)(b * NSEQ) * QKV_STR + KOFS + h * HDIM + 8 * hi;
  const short* vtb0 = vt + ((size_t)(b * HN + h) * 128) * 1024 + 8 * hi;

  int ct = __ffs((int)am) - 1;           // first active tile (am != 0 always)
  bfrag ka0, ka1, ka2, ka3;
  {
    const short* kr = kbase0 + (size_t)(ct * 64 + lm) * QKV_STR;
    ka0 = *(const bfrag*)(kr);
    ka1 = *(const bfrag*)(kr + 32);
    ka2 = *(const bfrag*)(kr + 64);
    ka3 = *(const bfrag*)(kr + 96);
  }

  while (ct >= 0) {
    const unsigned rem = am & ~((2u << ct) - 1);
    const int nct = rem ? (__ffs((int)rem) - 1) : -1;
    const bool do_s = (uni >> ct) & 1;
    const bool do_w = (wmask >> ct) & 1;

    // ---- QK^T with streaming K prefetch
    facc sacc[4] = {};
#pragma unroll
    for (int f = 0; f < 4; ++f) {
      const int pct = (f < 3) ? ct : (nct >= 0 ? nct : ct);
      const int pfr = (f < 3) ? 16 * (f + 1) : 0;
      const short* krn = kbase0 + (size_t)(pct * 64 + pfr + lm) * QKV_STR;
      bfrag kn0 = *(const bfrag*)(krn);
      bfrag kn1 = *(const bfrag*)(krn + 32);
      bfrag kn2 = *(const bfrag*)(krn + 64);
      bfrag kn3 = *(const bfrag*)(krn + 96);
      sacc[f] = MFMA16(qf[0], ka0, sacc[f]);
      sacc[f] = MFMA16(qf[1], ka1, sacc[f]);
      sacc[f] = MFMA16(qf[2], ka2, sacc[f]);
      sacc[f] = MFMA16(qf[3], ka3, sacc[f]);
      ka0 = kn0; ka1 = kn1; ka2 = kn2; ka3 = kn3;
    }

    // ---- hoist V loads (ks=0) so they fly under exp/LDS
    const short* vtb = vtb0 + ct * 64;
    bfrag vb0[8];
#pragma unroll
    for (int df = 0; df < 8; ++df)
      vb0[df] = *(const bfrag*)&vtb[(size_t)(16 * df + lm) * 1024];

    // ---- exp + masks + partial sums + LDS P write (XOR-swizzled)
#pragma unroll
    for (int f = 0; f < 4; ++f) {
      const int col = ct * 64 + 16 * f + lm;
#pragma unroll
      for (int rg = 0; rg < 4; ++rg) {
        const int row = nbase + 4 * hi + rg;
        float e = __expf(sacc[f][rg] * SCALE);
        e = (col <= row) ? e : 0.f;
        float es = ((sel4[rg] >> ct) & 1) ? e : 0.f;
        float ew = (row - col <= 64) ? e : 0.f;
        ps_s[rg] += es;
        ps_w[rg] += ew;
        const int srow = 4 * hi + rg;
        const int sidx = (64 * srow + 16 * f + lm) ^ ((srow & 7) << 3);
        if (do_s) p_slc[sidx] = f2bf(es);
        if (do_w) p_swa[sidx] = f2bf(ew);
      }
    }
    __syncthreads();

    // ---- PV ks=0 (vb0 preloaded); load vb1 during the MFMAs
    {
      const int ridx0 = (64 * lm + 8 * hi) ^ ((lm & 7) << 3);
      bfrag pas = {}, paw = {};
      if (do_s) pas = *(const bfrag*)&p_slc[ridx0];
      if (do_w) paw = *(const bfrag*)&p_swa[ridx0];
      bfrag vb1[8];
#pragma unroll
      for (int df = 0; df < 8; ++df)
        vb1[df] = *(const bfrag*)&vtb[(size_t)(16 * df + lm) * 1024 + 32];
#pragma unroll
      for (int df = 0; df < 8; ++df) {
        if (do_s) acc_slc[df] = MFMA16(pas, vb0[df], acc_slc[df]);
        if (do_w) acc_swa[df] = MFMA16(paw, vb0[df], acc_swa[df]);
      }
      const int ridx1 = (64 * lm + 8 * hi + 32) ^ ((lm & 7) << 3);
      bfrag pas1 = {}, paw1 = {};
      if (do_s) pas1 = *(const bfrag*)&p_slc[ridx1];
      if (do_w) paw1 = *(const bfrag*)&p_swa[ridx1];
#pragma unroll
      for (int df = 0; df < 8; ++df) {
        if (do_s) acc_slc[df] = MFMA16(pas1, vb1[df], acc_slc[df]);
        if (do_w) acc_swa[df] = MFMA16(paw1, vb1[df], acc_swa[df]);
      }
    }
    __syncthreads();
    ct = nct;
  }

  // ---- compressed branch: O_cmp = Pc[16x16] * Vc[16x128], K padded to 32
  facc acc_cmp[8] = {};
  {
    bfrag pa = {};
    if (hi < 2)
      pa = *(const bfrag*)&pc[((size_t)(b * HN + h) * NSEQ + nbase + lm) * 16 + 8 * hi];
#pragma unroll
    for (int df = 0; df < 8; ++df) {
      bfrag vb = {};
      if (hi < 2)
        vb = *(const bfrag*)&vct[(((size_t)(b * HN + h) * 128) + 16 * df + lm) * 16 + 8 * hi];
      acc_cmp[df] = MFMA16(pa, vb, acc_cmp[df]);
    }
  }

  // ---- denominators: reduce across the 16 col-lanes
#pragma unroll
  for (int m = 1; m < 16; m <<= 1) {
#pragma unroll
    for (int rg = 0; rg < 4; ++rg) {
      ps_s[rg] += __shfl_xor(ps_s[rg], m);
      ps_w[rg] += __shfl_xor(ps_w[rg], m);
    }
  }

  float inv_s[4], inv_w[4], gcv[4], gsv[4], gwv[4];
#pragma unroll
  for (int rg = 0; rg < 4; ++rg) {
    inv_s[rg] = 1.0f / ps_s[rg];
    inv_w[rg] = 1.0f / ps_w[rg];
    const short* gp = qkv + (size_t)(b * NSEQ + nbase + 4 * hi + rg) * QKV_STR + GOFS;
    gcv[rg] = 1.0f / (1.0f + __expf(-bf2f(gp[h])));
    gsv[rg] = 1.0f / (1.0f + __expf(-bf2f(gp[16 + h])));
    gwv[rg] = 1.0f / (1.0f + __expf(-bf2f(gp[32 + h])));
  }

  short* obase = o + (size_t)(b * NSEQ + nbase) * 2048 + h * HDIM;
#pragma unroll
  for (int df = 0; df < 8; ++df)
#pragma unroll
    for (int rg = 0; rg < 4; ++rg) {
      float val = gcv[rg] * acc_cmp[df][rg] +
                  gsv[rg] * acc_slc[df][rg] * inv_s[rg] +
                  gwv[rg] * acc_swa[df][rg] * inv_w[rg];
      obase[(size_t)(4 * hi + rg) * 2048 + 16 * df + lm] = f2bf(val);
    }
}

// ------------------------------------------------------------------
extern "C" void kernel_launch(void* const* d_in, const int* in_sizes, int n_in,
                              void* d_out, int out_size, void* d_ws, size_t ws_size,
                              hipStream_t stream) {
  const float* x  = (const float*)d_in[0];
  const float* Wq = (const float*)d_in[1];
  const float* Wk = (const float*)d_in[2];
  const float* Wv = (const float*)d_in[3];
  const float* Wg = (const float*)d_in[4];
  const float* Wo = (const float*)d_in[5];
  float* out = (float*)d_out;

  char* w = (char*)d_ws;
  short* x_bf = (short*)w;            // 8.4 MB (reused as o_bf)
  short* o_bf = x_bf;
  w += (size_t)2048 * 2048 * 2;
  short* w_t  = (short*)w;            // 25.7 MB (reused for Wo^T)
  w += (size_t)6272 * 2048 * 2;
  short* qkv  = (short*)w;            // 25.7 MB (incl. gate cols 6144..6271)
  w += (size_t)2048 * 6272 * 2;
  float* kc   = (float*)w; w += (size_t)65536 * 4;
  short* vct  = (short*)w; w += (size_t)65536 * 2;
  short* pcb  = (short*)w; w += (size_t)524288 * 2;
  int*   sel  = (int*)w;   w += (size_t)32768 * 4;
  short* vt   = (short*)w; w += (size_t)4194304 * 2;  // 8.4 MB
  float2* tbl = (float2*)w; w += (size_t)65536 * 8;   // 0.5 MB

  const dim3 blk(256);
  prep<<<dim3(64, 64, 5), blk, 0, stream>>>(Wq, Wk, Wv, Wg, x, w_t, x_bf);
  rope_tbl<<<256, blk, 0, stream>>>(tbl);
  gemm_bf16_bt<short><<<784, blk, 0, stream>>>(x_bf, w_t, qkv, 2048, 6272, 2048);
  rope_qk<<<2048, blk, 0, stream>>>(qkv, tbl);
  block_mean<<<256, blk, 0, stream>>>(qkv + KOFS, kc);
  v_transpose<<<dim3(16, 16, 2), blk, 0, stream>>>(qkv, vt, vct);
  cmp_sel<<<128, blk, 0, stream>>>(qkv, kc, pcb, sel);
  transpose_cast<<<dim3(64, 64), blk, 0, stream>>>(Wo, w_t);
  attn_mfma<<<2048, dim3(64), 0, stream>>>(qkv, vt, vct, pcb, sel, o_bf);
  gemm_bf16_bt<float><<<256, blk, 0, stream>>>(o_bf, w_t, out, 2048, 2048, 2048);
}

// Round 6
// 260.522 us; speedup vs baseline: 6.8821x; 1.1640x over previous
//
#include <hip/hip_runtime.h>
#include <hip/hip_bf16.h>

// NSA forward: B=2, N=1024, D=2048, H=16, HD=128, BS=64, SEL=8, WIN=64
#define HN   16
#define HDIM 128
#define NSEQ 1024
#define NBLK 16
#define BSZ  64
#define SCALE 0.08838834764831845f
#define QKV_STR 6400   // row stride of fused qkv+gate buffer (bf16), padded to 25*256
#define KOFS 2048
#define VOFS 4096
#define GOFS 6144

typedef __attribute__((ext_vector_type(8))) short bfrag;   // 8 bf16 (4 VGPRs)
typedef __attribute__((ext_vector_type(4))) float facc;    // MFMA accumulator

__device__ __forceinline__ float bf2f(short s) {
  union { unsigned u; float f; } cv;
  cv.u = ((unsigned)(unsigned short)s) << 16;
  return cv.f;
}
__device__ __forceinline__ short f2bf(float f) {
  unsigned u = __float_as_uint(f);
  u = (u + 0x7fff + ((u >> 16) & 1)) >> 16;  // RNE
  return (short)u;
}

#define ASYNC16(gp, lp)                                                    \
  __builtin_amdgcn_global_load_lds(                                        \
      (const __attribute__((address_space(1))) void*)(gp),                 \
      (__attribute__((address_space(3))) void*)(lp), 16, 0, 0)

#define MFMA16(a, b, c) __builtin_amdgcn_mfma_f32_16x16x32_bf16(a, b, c, 0, 0, 0)

// ------------------------------------------------------------------
// prep: z=0..2 -> Wq/Wk/Wv transpose-cast into w_t rows z*2048..
//       z=3   -> Wg [2048][48] transposed + zero-padded to rows 6144..6271
//       z=4   -> x cast to bf16 (no transpose)
// ------------------------------------------------------------------
__global__ __launch_bounds__(256) void prep(const float* __restrict__ Wq,
                                            const float* __restrict__ Wk,
                                            const float* __restrict__ Wv,
                                            const float* __restrict__ Wg,
                                            const float* __restrict__ x,
                                            short* __restrict__ w_t,
                                            short* __restrict__ x_bf) {
  __shared__ float tile[32][33];
  const int z = blockIdx.z;
  const int bx = blockIdx.x * 32, by = blockIdx.y * 32;
  const int tx = threadIdx.x & 31, ty = threadIdx.x >> 5;
  if (z == 4) {
#pragma unroll
    for (int i = 0; i < 4; ++i) {
      const int row = by + ty + 8 * i;
      x_bf[(size_t)row * 2048 + bx + tx] = f2bf(x[(size_t)row * 2048 + bx + tx]);
    }
    return;
  }
  if (z == 3) {
    if (blockIdx.x >= 4) return;  // only 128 dst rows
#pragma unroll
    for (int i = 0; i < 4; ++i) {
      const int c = bx + tx;
      tile[ty + 8 * i][tx] = (c < 48) ? Wg[(size_t)(by + ty + 8 * i) * 48 + c] : 0.f;
    }
    __syncthreads();
#pragma unroll
    for (int i = 0; i < 4; ++i)
      w_t[(size_t)(GOFS + bx + ty + 8 * i) * 2048 + by + tx] = f2bf(tile[tx][ty + 8 * i]);
    return;
  }
  const float* src = (z == 0) ? Wq : (z == 1) ? Wk : Wv;
#pragma unroll
  for (int i = 0; i < 4; ++i)
    tile[ty + 8 * i][tx] = src[(size_t)(by + ty + 8 * i) * 2048 + bx + tx];
  __syncthreads();
#pragma unroll
  for (int i = 0; i < 4; ++i)
    w_t[(size_t)(z * 2048 + bx + ty + 8 * i) * 2048 + by + tx] = f2bf(tile[tx][ty + 8 * i]);
}

// ------------------------------------------------------------------
// Wo transpose (reuses w_t after qkv gemm)
// ------------------------------------------------------------------
__global__ __launch_bounds__(256) void transpose_cast(const float* __restrict__ src,
                                                      short* __restrict__ dst) {
  __shared__ float tile[32][33];
  const int bx = blockIdx.x * 32, by = blockIdx.y * 32;
  const int tx = threadIdx.x & 31, ty = threadIdx.x >> 5;
#pragma unroll
  for (int i = 0; i < 4; ++i)
    tile[ty + 8 * i][tx] = src[(size_t)(by + ty + 8 * i) * 2048 + bx + tx];
  __syncthreads();
#pragma unroll
  for (int i = 0; i < 4; ++i)
    dst[(size_t)(bx + ty + 8 * i) * 2048 + by + tx] = f2bf(tile[tx][ty + 8 * i]);
}

// ------------------------------------------------------------------
// 8-phase 256x256 bf16 GEMM (T2+T3+T4+T5): C[M][N] = A[M][K]*Bt[N][K]^T
// 512 thr = 8 waves (2M x 4N); BK=64; 128KB LDS dbuf; counted vmcnt.
// grid = 8 * (N/256): row-block = L&7 (one per XCD), col = L>>3.
// LDS tiles XOR-swizzled: inverse-swz global src + swz ds_read (rule 21).
// ------------------------------------------------------------------
__global__ __launch_bounds__(512, 1) void gemm256(const short* __restrict__ A,
                                                  const short* __restrict__ Bt,
                                                  short* __restrict__ C,
                                                  int M, int N, int K) {
  __shared__ short lds[2][2][16384];  // [buf][A/B][256*64]
  const int t = threadIdx.x;
  const int l = t & 63, w = t >> 6;
  const int wm = w >> 2, wn = w & 3;
  const int lm = l & 15, hi = l >> 4;
  const int lanexor = (lm & 7) << 3;            // shorts
  const int kk0 = (hi * 8) ^ lanexor;           // ks=0 column (shorts)
  const int L = blockIdx.x;
  const int row0 = (L & 7) * 256, col0 = (L >> 3) * 256;
  const int nt = K >> 6;

  // staging coords: thread t -> rows (t>>3), (t>>3)+64; col chunk inverse-swz
  const int srow = t >> 3;
  const int scol = 8 * ((t & 7) ^ (srow & 7));
  const short* Ab = A + (size_t)(row0 + srow) * K + scol;
  const short* Bb = Bt + (size_t)(col0 + srow) * K + scol;

#define STAGE(mat, srcbase, h, tau, buf)                                     \
  {                                                                          \
    const short* g_ = (srcbase) + (size_t)(h) * 128 * K + (size_t)(tau) * 64;\
    short* d_ = &lds[buf][mat][(h) * 8192 + t * 8];                          \
    ASYNC16(g_, d_);                                                         \
    ASYNC16(g_ + (size_t)64 * K, d_ + 4096);                                 \
  }

  facc acc[8][4] = {};
  bfrag af[8], bf0[4], bf1[4];

  // ---- prologue: A(0),B(0) -> buf0 ; B(1) -> buf1
  STAGE(0, Ab, 0, 0, 0); STAGE(0, Ab, 1, 0, 0);
  STAGE(1, Bb, 0, 0, 0); STAGE(1, Bb, 1, 0, 0);
  STAGE(1, Bb, 0, 1, 1); STAGE(1, Bb, 1, 1, 1);
  asm volatile("s_waitcnt vmcnt(4)" ::: "memory");
  __builtin_amdgcn_s_barrier();

  for (int tau = 0; tau < nt; ++tau) {
    const int c = tau & 1;
    const int tA = (tau + 1 < nt) ? tau + 1 : nt - 1;  // src tile for A stages
    const int tB = (tau + 2 < nt) ? tau + 2 : nt - 1;  // src tile for B stages

#define DS_A(qm)                                                             \
  _Pragma("unroll") for (int ii = 0; ii < 4; ++ii) {                         \
    const int row_ = wm * 128 + (qm) * 64 + ii * 16 + lm;                    \
    af[ii * 2 + 0] = *(const bfrag*)&lds[c][0][row_ * 64 + kk0];             \
    af[ii * 2 + 1] = *(const bfrag*)&lds[c][0][row_ * 64 + (kk0 ^ 32)];      \
  }
#define DS_B(qn, arr)                                                        \
  _Pragma("unroll") for (int jj = 0; jj < 2; ++jj) {                         \
    const int row_ = wn * 64 + (qn) * 32 + jj * 16 + lm;                     \
    arr[jj * 2 + 0] = *(const bfrag*)&lds[c][1][row_ * 64 + kk0];            \
    arr[jj * 2 + 1] = *(const bfrag*)&lds[c][1][row_ * 64 + (kk0 ^ 32)];     \
  }
#define QUAD(qm, qn, arr)                                                    \
  _Pragma("unroll") for (int ii = 0; ii < 4; ++ii)                           \
  _Pragma("unroll") for (int jj = 0; jj < 2; ++jj) {                         \
    acc[(qm)*4+ii][(qn)*2+jj] = MFMA16(af[ii*2+0], arr[jj*2+0], acc[(qm)*4+ii][(qn)*2+jj]); \
    acc[(qm)*4+ii][(qn)*2+jj] = MFMA16(af[ii*2+1], arr[jj*2+1], acc[(qm)*4+ii][(qn)*2+jj]); \
  }

    // ---- P0: read A(qm0)+B(qn0); stage A-half0(tau+1) -> buf c^1
    DS_A(0); DS_B(0, bf0);
    STAGE(0, Ab, 0, tA, c ^ 1);
    __builtin_amdgcn_s_barrier();
    asm volatile("s_waitcnt lgkmcnt(0)" ::: "memory");
    __builtin_amdgcn_sched_barrier(0);
    __builtin_amdgcn_s_setprio(1);
    QUAD(0, 0, bf0);
    __builtin_amdgcn_s_setprio(0);
    __builtin_amdgcn_s_barrier();

    // ---- P1: read B(qn1); stage A-half1(tau+1) -> buf c^1
    DS_B(1, bf1);
    STAGE(0, Ab, 1, tA, c ^ 1);
    __builtin_amdgcn_s_barrier();
    asm volatile("s_waitcnt lgkmcnt(0)" ::: "memory");
    __builtin_amdgcn_sched_barrier(0);
    __builtin_amdgcn_s_setprio(1);
    QUAD(0, 1, bf1);
    __builtin_amdgcn_s_setprio(0);
    __builtin_amdgcn_s_barrier();

    // ---- P2: read A(qm1); stage B-half0(tau+2) -> buf c (B last read P1)
    DS_A(1);
    STAGE(1, Bb, 0, tB, c);
    __builtin_amdgcn_s_barrier();
    asm volatile("s_waitcnt lgkmcnt(0)" ::: "memory");
    __builtin_amdgcn_sched_barrier(0);
    __builtin_amdgcn_s_setprio(1);
    QUAD(1, 1, bf1);
    __builtin_amdgcn_s_setprio(0);
    __builtin_amdgcn_s_barrier();

    // ---- P3: stage B-half1(tau+2) -> buf c; MFMA from regs; counted vmcnt
    STAGE(1, Bb, 1, tB, c);
    __builtin_amdgcn_s_setprio(1);
    QUAD(1, 0, bf0);
    __builtin_amdgcn_s_setprio(0);
    asm volatile("s_waitcnt vmcnt(4)" ::: "memory");
    __builtin_amdgcn_s_barrier();
  }

  // ---- epilogue
#pragma unroll
  for (int i = 0; i < 8; ++i)
#pragma unroll
    for (int j = 0; j < 4; ++j)
#pragma unroll
      for (int rr = 0; rr < 4; ++rr)
        C[(size_t)(row0 + wm * 128 + i * 16 + hi * 4 + rr) * N +
          col0 + wn * 64 + j * 16 + lm] = f2bf(acc[i][j][rr]);
#undef STAGE
#undef DS_A
#undef DS_B
#undef QUAD
}

// ------------------------------------------------------------------
// bf16 MFMA GEMM (m97 128^2): C[M][N] = A[M][K] * Bt[N][K]^T (out proj)
// ------------------------------------------------------------------
__device__ __forceinline__ void store_c(float* p, float v) { *p = v; }
__device__ __forceinline__ void store_c(short* p, float v) { *p = f2bf(v); }

template <typename OT>
__global__ __launch_bounds__(256) void gemm_bf16_bt(const short* __restrict__ A,
                                                    const short* __restrict__ Bt,
                                                    OT* __restrict__ C,
                                                    int M, int N, int K) {
  __shared__ short As[128 * 32];
  __shared__ short Bs[128 * 32];
  const int t = threadIdx.x;
  const int l = t & 63, w = t >> 6;
  const int wr = w >> 1, wc = w & 1;
  const int nwg = gridDim.x;
  const int L = blockIdx.x;
  const int wg = (L & 7) * (nwg >> 3) + (L >> 3);
  const int nrow = M >> 7;
  const int row0 = (wg % nrow) * 128, col0 = (wg / nrow) * 128;
  facc acc[4][4] = {};

  const int sr = t >> 2;
  const int sk = (t & 3) * 8;
  const short* Ag0 = A + (size_t)(row0 + sr) * K + sk;
  const short* Ag1 = Ag0 + (size_t)64 * K;
  const short* Bg0 = Bt + (size_t)(col0 + sr) * K + sk;
  const short* Bg1 = Bg0 + (size_t)64 * K;
  short* la = As + t * 8;
  short* lb = Bs + t * 8;

  const int lm = l & 15;
  const int lk = (l >> 4) * 8;

  for (int k0 = 0; k0 < K; k0 += 32) {
    ASYNC16(Ag0 + k0, la);
    ASYNC16(Ag1 + k0, la + 2048);
    ASYNC16(Bg0 + k0, lb);
    ASYNC16(Bg1 + k0, lb + 2048);
    __syncthreads();
    bfrag af[4], bf[4];
#pragma unroll
    for (int i = 0; i < 4; ++i)
      af[i] = *(const bfrag*)&As[(wr * 64 + i * 16 + lm) * 32 + lk];
#pragma unroll
    for (int j = 0; j < 4; ++j)
      bf[j] = *(const bfrag*)&Bs[(wc * 64 + j * 16 + lm) * 32 + lk];
#pragma unroll
    for (int i = 0; i < 4; ++i)
#pragma unroll
      for (int j = 0; j < 4; ++j)
        acc[i][j] = MFMA16(af[i], bf[j], acc[i][j]);
    __syncthreads();
  }

  const int orow = row0 + wr * 64 + (l >> 4) * 4;
  const int ocol = col0 + wc * 64 + lm;
#pragma unroll
  for (int i = 0; i < 4; ++i)
#pragma unroll
    for (int j = 0; j < 4; ++j)
#pragma unroll
      for (int rr = 0; rr < 4; ++rr)
        store_c(&C[(size_t)(orow + i * 16 + rr) * N + ocol + j * 16], acc[i][j][rr]);
}

// ------------------------------------------------------------------
// RoPE cos/sin table [n][d] (d<64), float2
// ------------------------------------------------------------------
__global__ __launch_bounds__(256) void rope_tbl(float2* __restrict__ tbl) {
  int i = blockIdx.x * 256 + threadIdx.x;  // 65536
  int d = i & 63, n = i >> 6;
  float inv = expf(-(float)d * (9.210340371976184f / 64.0f));
  float sn, cs;
  sincosf((float)n * inv, &sn, &cs);
  tbl[i] = make_float2(cs, sn);
}

// ------------------------------------------------------------------
// RoPE in place on q AND k slices, table-based, 8 dims/thread
// ------------------------------------------------------------------
__global__ __launch_bounds__(256) void rope_qk(short* __restrict__ qkv,
                                               const float2* __restrict__ tbl) {
  int i = blockIdx.x * 256 + threadIdx.x;  // 524288
  int c = i & 7;
  int h = (i >> 3) & 15;
  int qk = (i >> 7) & 1;
  int n = (i >> 8) & 1023;
  int b = i >> 18;
  short* base = qkv + (size_t)(b * NSEQ + n) * QKV_STR + qk * KOFS + h * HDIM + c * 8;
  const float2* tp = tbl + n * 64 + c * 8;
  bfrag t1 = *(const bfrag*)base, t2 = *(const bfrag*)(base + 64);
  bfrag o1, o2;
#pragma unroll
  for (int j = 0; j < 8; ++j) {
    float2 cssn = tp[j];
    float a = bf2f(t1[j]), bb = bf2f(t2[j]);
    o1[j] = f2bf(a * cssn.x - bb * cssn.y);
    o2[j] = f2bf(a * cssn.y + bb * cssn.x);
  }
  *(bfrag*)base = o1;
  *(bfrag*)(base + 64) = o2;
}

// ------------------------------------------------------------------
// Block mean (roped K) -> f32 kc [b][m][h][d]
// ------------------------------------------------------------------
__global__ __launch_bounds__(256) void block_mean(const short* __restrict__ src,
                                                  float* __restrict__ dst) {
  int i = blockIdx.x * 256 + threadIdx.x;  // 65536
  int d = i & 127;
  int h = (i >> 7) & 15;
  int m = (i >> 11) & 15;
  int b = i >> 15;
  const short* p = src + (size_t)(b * NSEQ + m * BSZ) * QKV_STR + h * HDIM + d;
  float acc = 0.f;
#pragma unroll 8
  for (int j = 0; j < 64; ++j) acc += bf2f(p[(size_t)j * QKV_STR]);
  dst[i] = acc * (1.0f / 64.0f);
}

// ------------------------------------------------------------------
// V transpose -> vt[b][h][d][n], fused V block-mean -> vct[b][h][d][m]
// ------------------------------------------------------------------
__global__ __launch_bounds__(256) void v_transpose(const short* __restrict__ qkv,
                                                   short* __restrict__ vt,
                                                   short* __restrict__ vct) {
  __shared__ short tile[64][136];
  const int n0 = blockIdx.x * 64;
  const int h = blockIdx.y, b = blockIdx.z;
  const int t = threadIdx.x;
#pragma unroll
  for (int it = 0; it < 4; ++it) {
    int idx = t + 256 * it;
    int row = idx >> 4, ch = idx & 15;
    *(bfrag*)&tile[row][ch * 8] =
        *(const bfrag*)&qkv[(size_t)(b * NSEQ + n0 + row) * QKV_STR + VOFS + h * HDIM + ch * 8];
  }
  __syncthreads();
#pragma unroll
  for (int it = 0; it < 4; ++it) {
    int idx = t + 256 * it;
    int d = idx >> 3, ch = idx & 7;
    bfrag tv;
    float s = 0.f;
#pragma unroll
    for (int j = 0; j < 8; ++j) {
      tv[j] = tile[ch * 8 + j][d];
      s += bf2f(tv[j]);
    }
    *(bfrag*)&vt[(((size_t)(b * HN + h) * 128) + d) * 1024 + n0 + ch * 8] = tv;
    s += __shfl_down(s, 4);
    s += __shfl_down(s, 2);
    s += __shfl_down(s, 1);
    if ((t & 7) == 0)
      vct[(((size_t)(b * HN + h) * 128) + d) * 16 + (n0 >> 6)] = f2bf(s * (1.0f / 64.0f));
  }
}

// ------------------------------------------------------------------
// Compressed probs (bf16 pc [b][h][n][16]) + top-8 selection bitmask
// ------------------------------------------------------------------
__global__ __launch_bounds__(256) void cmp_sel(const short* __restrict__ qkv,
                                               const float* __restrict__ kc,
                                               short* __restrict__ pc,
                                               int* __restrict__ sel) {
  int i = blockIdx.x * 256 + threadIdx.x;  // B*H*N = 32768
  int n = i & 1023;
  int h = (i >> 10) & 15;
  int b = i >> 14;
  const short* qp = qkv + (size_t)(b * NSEQ + n) * QKV_STR + h * HDIM;
  float qf[HDIM];
#pragma unroll
  for (int d0 = 0; d0 < HDIM; d0 += 8) {
    bfrag qv = *(const bfrag*)&qp[d0];
#pragma unroll
    for (int dd = 0; dd < 8; ++dd) qf[d0 + dd] = bf2f(qv[dd]);
  }
  const int nv = (n + 1) >> 6;
  float s[NBLK];
  float mx = -1e30f;
  for (int m = 0; m < nv; ++m) {
    const float* kp = kc + ((size_t)((b * NBLK + m) * HN + h) << 7);
    float dot = 0.f;
    for (int d = 0; d < HDIM; d += 4) {
      const float4 kv = *(const float4*)&kp[d];
      dot += qf[d] * kv.x + qf[d + 1] * kv.y + qf[d + 2] * kv.z + qf[d + 3] * kv.w;
    }
    s[m] = dot * SCALE;
    mx = fmaxf(mx, s[m]);
  }
  float den = 0.f;
  for (int m = 0; m < nv; ++m) { s[m] = __expf(s[m] - mx); den += s[m]; }
  const float rden = (nv > 0) ? 1.0f / den : 0.f;
  float p[NBLK];
#pragma unroll
  for (int m = 0; m < NBLK; ++m) p[m] = (m < nv) ? s[m] * rden : 0.f;
  bfrag o0, o1;
#pragma unroll
  for (int m = 0; m < 8; ++m) { o0[m] = f2bf(p[m]); o1[m] = f2bf(p[m + 8]); }
  bfrag* pout = (bfrag*)(pc + (size_t)i * 16);
  pout[0] = o0; pout[1] = o1;
  p[n >> 6] += 2.0f;
  int mask = 0;
#pragma unroll
  for (int ss = 0; ss < 8; ++ss) {
    int best = 0;
    float bv = -1e30f;
#pragma unroll
    for (int m = 0; m < NBLK; ++m)
      if (p[m] > bv) { bv = p[m]; best = m; }
    mask |= 1 << best;
    p[best] = -1e30f;
  }
  sel[i] = mask;
}

// ------------------------------------------------------------------
// MFMA attention. One wave per (b,h,16-row tile). XCD-swizzled grid,
// heavy-first. Pipelined K loads, V loads hoisted, gating fused.
// ------------------------------------------------------------------
__global__ __launch_bounds__(64, 2) void attn_mfma(
    const short* __restrict__ qkv, const short* __restrict__ vt,
    const short* __restrict__ vct, const short* __restrict__ pc,
    const int* __restrict__ sel, short* __restrict__ o) {
  const int fid = blockIdx.x;
  const int xcd = fid & 7;
  const int idx = fid >> 3;              // 0..255
  const int pair = (xcd << 2) | (idx & 3);
  const int rt = 63 - (idx >> 2);        // heavy tiles first
  const int h = pair & 15, b = pair >> 4;

  const int l = threadIdx.x;
  const int lm = l & 15, hi = l >> 4;
  const int nbase = rt * 16;

  __shared__ short p_slc[1024];
  __shared__ short p_swa[1024];

  // Q A-fragments
  const short* qrow = qkv + (size_t)(b * NSEQ + nbase + lm) * QKV_STR + h * HDIM;
  bfrag qf[4];
#pragma unroll
  for (int ks = 0; ks < 4; ++ks) qf[ks] = *(const bfrag*)&qrow[32 * ks + 8 * hi];

  // selection bits
  int selrow = sel[(size_t)(b * HN + h) * NSEQ + nbase + lm];
  int uni = selrow;
#pragma unroll
  for (int m = 1; m < 16; m <<= 1) uni |= __shfl_xor(uni, m);
  int sel4[4];
#pragma unroll
  for (int rg = 0; rg < 4; ++rg) sel4[rg] = __shfl(selrow, 4 * hi + rg);

  const int thi = nbase >> 6;
  const int tlo = (nbase >= 64) ? ((nbase - 64) >> 6) : 0;
  const int wmask = (int)((2u << thi) - (1u << tlo));
  const unsigned am = (unsigned)(uni | wmask) & (unsigned)((2u << thi) - 1);

  facc acc_slc[8] = {}, acc_swa[8] = {};
  float ps_s[4] = {0.f, 0.f, 0.f, 0.f}, ps_w[4] = {0.f, 0.f, 0.f, 0.f};

  const short* kbase0 = qkv + (size_t)(b * NSEQ) * QKV_STR + KOFS + h * HDIM + 8 * hi;
  const short* vtb0 = vt + ((size_t)(b * HN + h) * 128) * 1024 + 8 * hi;

  int ct = __ffs((int)am) - 1;           // first active tile (am != 0 always)
  bfrag ka0, ka1, ka2, ka3;
  {
    const short* kr = kbase0 + (size_t)(ct * 64 + lm) * QKV_STR;
    ka0 = *(const bfrag*)(kr);
    ka1 = *(const bfrag*)(kr + 32);
    ka2 = *(const bfrag*)(kr + 64);
    ka3 = *(const bfrag*)(kr + 96);
  }

  while (ct >= 0) {
    const unsigned rem = am & ~((2u << ct) - 1);
    const int nct = rem ? (__ffs((int)rem) - 1) : -1;
    const bool do_s = (uni >> ct) & 1;
    const bool do_w = (wmask >> ct) & 1;

    // ---- QK^T with streaming K prefetch
    facc sacc[4] = {};
#pragma unroll
    for (int f = 0; f < 4; ++f) {
      const int pct = (f < 3) ? ct : (nct >= 0 ? nct : ct);
      const int pfr = (f < 3) ? 16 * (f + 1) : 0;
      const short* krn = kbase0 + (size_t)(pct * 64 + pfr + lm) * QKV_STR;
      bfrag kn0 = *(const bfrag*)(krn);
      bfrag kn1 = *(const bfrag*)(krn + 32);
      bfrag kn2 = *(const bfrag*)(krn + 64);
      bfrag kn3 = *(const bfrag*)(krn + 96);
      sacc[f] = MFMA16(qf[0], ka0, sacc[f]);
      sacc[f] = MFMA16(qf[1], ka1, sacc[f]);
      sacc[f] = MFMA16(qf[2], ka2, sacc[f]);
      sacc[f] = MFMA16(qf[3], ka3, sacc[f]);
      ka0 = kn0; ka1 = kn1; ka2 = kn2; ka3 = kn3;
    }

    // ---- hoist V loads (ks=0) so they fly under exp/LDS
    const short* vtb = vtb0 + ct * 64;
    bfrag vb0[8];
#pragma unroll
    for (int df = 0; df < 8; ++df)
      vb0[df] = *(const bfrag*)&vtb[(size_t)(16 * df + lm) * 1024];

    // ---- exp + masks + partial sums + LDS P write (XOR-swizzled)
#pragma unroll
    for (int f = 0; f < 4; ++f) {
      const int col = ct * 64 + 16 * f + lm;
#pragma unroll
      for (int rg = 0; rg < 4; ++rg) {
        const int row = nbase + 4 * hi + rg;
        float e = __expf(sacc[f][rg] * SCALE);
        e = (col <= row) ? e : 0.f;
        float es = ((sel4[rg] >> ct) & 1) ? e : 0.f;
        float ew = (row - col <= 64) ? e : 0.f;
        ps_s[rg] += es;
        ps_w[rg] += ew;
        const int srow = 4 * hi + rg;
        const int sidx = (64 * srow + 16 * f + lm) ^ ((srow & 7) << 3);
        if (do_s) p_slc[sidx] = f2bf(es);
        if (do_w) p_swa[sidx] = f2bf(ew);
      }
    }
    __syncthreads();

    // ---- PV ks=0 (vb0 preloaded); load vb1 during the MFMAs
    {
      const int ridx0 = (64 * lm + 8 * hi) ^ ((lm & 7) << 3);
      bfrag pas = {}, paw = {};
      if (do_s) pas = *(const bfrag*)&p_slc[ridx0];
      if (do_w) paw = *(const bfrag*)&p_swa[ridx0];
      bfrag vb1[8];
#pragma unroll
      for (int df = 0; df < 8; ++df)
        vb1[df] = *(const bfrag*)&vtb[(size_t)(16 * df + lm) * 1024 + 32];
#pragma unroll
      for (int df = 0; df < 8; ++df) {
        if (do_s) acc_slc[df] = MFMA16(pas, vb0[df], acc_slc[df]);
        if (do_w) acc_swa[df] = MFMA16(paw, vb0[df], acc_swa[df]);
      }
      const int ridx1 = (64 * lm + 8 * hi + 32) ^ ((lm & 7) << 3);
      bfrag pas1 = {}, paw1 = {};
      if (do_s) pas1 = *(const bfrag*)&p_slc[ridx1];
      if (do_w) paw1 = *(const bfrag*)&p_swa[ridx1];
#pragma unroll
      for (int df = 0; df < 8; ++df) {
        if (do_s) acc_slc[df] = MFMA16(pas1, vb1[df], acc_slc[df]);
        if (do_w) acc_swa[df] = MFMA16(paw1, vb1[df], acc_swa[df]);
      }
    }
    __syncthreads();
    ct = nct;
  }

  // ---- compressed branch: O_cmp = Pc[16x16] * Vc[16x128], K padded to 32
  facc acc_cmp[8] = {};
  {
    bfrag pa = {};
    if (hi < 2)
      pa = *(const bfrag*)&pc[((size_t)(b * HN + h) * NSEQ + nbase + lm) * 16 + 8 * hi];
#pragma unroll
    for (int df = 0; df < 8; ++df) {
      bfrag vb = {};
      if (hi < 2)
        vb = *(const bfrag*)&vct[(((size_t)(b * HN + h) * 128) + 16 * df + lm) * 16 + 8 * hi];
      acc_cmp[df] = MFMA16(pa, vb, acc_cmp[df]);
    }
  }

  // ---- denominators: reduce across the 16 col-lanes
#pragma unroll
  for (int m = 1; m < 16; m <<= 1) {
#pragma unroll
    for (int rg = 0; rg < 4; ++rg) {
      ps_s[rg] += __shfl_xor(ps_s[rg], m);
      ps_w[rg] += __shfl_xor(ps_w[rg], m);
    }
  }

  float inv_s[4], inv_w[4], gcv[4], gsv[4], gwv[4];
#pragma unroll
  for (int rg = 0; rg < 4; ++rg) {
    inv_s[rg] = 1.0f / ps_s[rg];
    inv_w[rg] = 1.0f / ps_w[rg];
    const short* gp = qkv + (size_t)(b * NSEQ + nbase + 4 * hi + rg) * QKV_STR + GOFS;
    gcv[rg] = 1.0f / (1.0f + __expf(-bf2f(gp[h])));
    gsv[rg] = 1.0f / (1.0f + __expf(-bf2f(gp[16 + h])));
    gwv[rg] = 1.0f / (1.0f + __expf(-bf2f(gp[32 + h])));
  }

  short* obase = o + (size_t)(b * NSEQ + nbase) * 2048 + h * HDIM;
#pragma unroll
  for (int df = 0; df < 8; ++df)
#pragma unroll
    for (int rg = 0; rg < 4; ++rg) {
      float val = gcv[rg] * acc_cmp[df][rg] +
                  gsv[rg] * acc_slc[df][rg] * inv_s[rg] +
                  gwv[rg] * acc_swa[df][rg] * inv_w[rg];
      obase[(size_t)(4 * hi + rg) * 2048 + 16 * df + lm] = f2bf(val);
    }
}

// ------------------------------------------------------------------
extern "C" void kernel_launch(void* const* d_in, const int* in_sizes, int n_in,
                              void* d_out, int out_size, void* d_ws, size_t ws_size,
                              hipStream_t stream) {
  const float* x  = (const float*)d_in[0];
  const float* Wq = (const float*)d_in[1];
  const float* Wk = (const float*)d_in[2];
  const float* Wv = (const float*)d_in[3];
  const float* Wg = (const float*)d_in[4];
  const float* Wo = (const float*)d_in[5];
  float* out = (float*)d_out;

  char* w = (char*)d_ws;
  short* x_bf = (short*)w;            // 8.4 MB (reused as o_bf)
  short* o_bf = x_bf;
  w += (size_t)2048 * 2048 * 2;
  short* w_t  = (short*)w;            // 26.2 MB (rows 6272..6399 unused pad)
  w += (size_t)6400 * 2048 * 2;
  short* qkv  = (short*)w;            // 26.2 MB (stride 6400; gate at 6144)
  w += (size_t)2048 * 6400 * 2;
  float* kc   = (float*)w; w += (size_t)65536 * 4;
  short* vct  = (short*)w; w += (size_t)65536 * 2;
  short* pcb  = (short*)w; w += (size_t)524288 * 2;
  int*   sel  = (int*)w;   w += (size_t)32768 * 4;
  short* vt   = (short*)w; w += (size_t)4194304 * 2;  // 8.4 MB
  float2* tbl = (float2*)w; w += (size_t)65536 * 8;   // 0.5 MB

  const dim3 blk(256);
  prep<<<dim3(64, 64, 5), blk, 0, stream>>>(Wq, Wk, Wv, Wg, x, w_t, x_bf);
  rope_tbl<<<256, blk, 0, stream>>>(tbl);
  gemm256<<<200, dim3(512), 0, stream>>>(x_bf, w_t, qkv, 2048, 6400, 2048);
  rope_qk<<<2048, blk, 0, stream>>>(qkv, tbl);
  block_mean<<<256, blk, 0, stream>>>(qkv + KOFS, kc);
  v_transpose<<<dim3(16, 16, 2), blk, 0, stream>>>(qkv, vt, vct);
  cmp_sel<<<128, blk, 0, stream>>>(qkv, kc, pcb, sel);
  transpose_cast<<<dim3(64, 64), blk, 0, stream>>>(Wo, w_t);
  attn_mfma<<<2048, dim3(64), 0, stream>>>(qkv, vt, vct, pcb, sel, o_bf);
  gemm_bf16_bt<float><<<256, blk, 0, stream>>>(o_bf, w_t, out, 2048, 2048, 2048);
}